// Round 6
// baseline (995.636 us; speedup 1.0000x reference)
//
#include <hip/hip_runtime.h>
#include <math.h>

#define HID 256
#define NBINS 4
#define NMIR 2000
#define NMRNA 20000
#define NG (NMRNA + NMIR)   // 22000 union gene space
#define BB 16
#define NP 2048
#define PD 1024
#define EREG 300000
#define EPM 320000
#define EPI 32000

typedef __attribute__((ext_vector_type(8))) short bf16x8;
typedef __attribute__((ext_vector_type(4))) float f32x4;

__device__ __forceinline__ float gelu_exact(float x) {
    return 0.5f * x * (1.0f + erff(x * 0.7071067811865475f));
}

// fp32 -> bf16 round-to-nearest-even (bits)
__device__ __forceinline__ unsigned short f2b(float f) {
    union { float f; unsigned int u; } v; v.f = f;
    unsigned int u = v.u + 0x7fffu + ((v.u >> 16) & 1u);
    return (unsigned short)(u >> 16);
}

__device__ __forceinline__ float b2f(unsigned short u) {
    union { unsigned int i; float f; } v; v.i = ((unsigned int)u) << 16;
    return v.f;
}

// blockDim.x == 256 assumed
__device__ __forceinline__ float block_reduce_sum(float v, float* red) {
    int c = threadIdx.x;
    red[c] = v;
    __syncthreads();
    for (int st = 128; st > 0; st >>= 1) {
        if (c < st) red[c] += red[c + st];
        __syncthreads();
    }
    float r = red[0];
    __syncthreads();
    return r;
}

// 256-thread block laid out as (b = t&15, kk = t>>4); reduce over kk, result to all
__device__ __forceinline__ float kred(float v, float* red, int b, int kk) {
    red[kk * 16 + b] = v;
    __syncthreads();
    for (int st = 8; st >= 1; st >>= 1) {
        if (kk < st) red[kk * 16 + b] += red[(kk + st) * 16 + b];
        __syncthreads();
    }
    float r = red[b];
    __syncthreads();
    return r;
}

// ================= conversions: emb->bf16 + reg weights->bf16 =================
#define CVT_EMB ((NG * HID) / 4096)              // 1375 blocks, 16 elems/thread
#define CVT_F2B ((2 * HID * HID) / 4096)         // 32
#define CVT_TOTAL (CVT_EMB + CVT_F2B)

__global__ __launch_bounds__(256) void k_cvt(
        const float* __restrict__ emb_mirna, const float* __restrict__ emb_mrna,
        unsigned short* __restrict__ embB_mir, unsigned short* __restrict__ embB_mrna,
        const float* __restrict__ regwA, const float* __restrict__ regwB,
        unsigned short* __restrict__ wb) {
    int bid = blockIdx.x;
    int t = threadIdx.x;
    if (bid < CVT_EMB) {
        const size_t NM = (size_t)NMIR * HID;  // 512000; 4096-block boundary aligned (125*4096)
        float4 v[4];
#pragma unroll
        for (int k = 0; k < 4; k++) {
            size_t e = (size_t)bid * 4096 + k * 1024 + t * 4;
            v[k] = (e < NM) ? *(const float4*)(emb_mirna + e)
                            : *(const float4*)(emb_mrna + (e - NM));
        }
#pragma unroll
        for (int k = 0; k < 4; k++) {
            size_t e = (size_t)bid * 4096 + k * 1024 + t * 4;
            ushort4 u = { f2b(v[k].x), f2b(v[k].y), f2b(v[k].z), f2b(v[k].w) };
            if (e < NM) *(ushort4*)(embB_mir + e) = u;
            else        *(ushort4*)(embB_mrna + (e - NM)) = u;
        }
        return;
    }
    bid -= CVT_EMB;
    {
        const size_t NW = (size_t)HID * HID;   // 65536; aligned at block 16
        float4 v[4];
#pragma unroll
        for (int k = 0; k < 4; k++) {
            size_t e = (size_t)bid * 4096 + k * 1024 + t * 4;
            v[k] = (e < NW) ? *(const float4*)(regwA + e)
                            : *(const float4*)(regwB + (e - NW));
        }
#pragma unroll
        for (int k = 0; k < 4; k++) {
            size_t e = (size_t)bid * 4096 + k * 1024 + t * 4;
            ushort4 u = { f2b(v[k].x), f2b(v[k].y), f2b(v[k].z), f2b(v[k].w) };
            *(ushort4*)(wb + e) = u;
        }
    }
}

// ================= counting-sort CSR build: ZERO global atomics =================
// reg edges (2*EREG, binned by dst node) -> NBR chunks; pat edges (EPM+EPI, binned
// by src gene) -> NBP chunks. Each chunk: LDS histogram -> plain coalesced stores.
#define NBR 16
#define NBP 8
#define PER_R ((2 * EREG + NBR - 1) / NBR)   // 37500
#define PER_P ((EPM + EPI + NBP - 1) / NBP)  // 44000

__global__ __launch_bounds__(1024) void k_hist(
        const int* __restrict__ dR1, const int* __restrict__ dR2,
        const int* __restrict__ sP1, const int* __restrict__ sP2,
        int* __restrict__ histR, int* __restrict__ histP) {
    __shared__ int lh[NG];
    int t = threadIdx.x, bid = blockIdx.x;
    for (int i = t; i < NG; i += 1024) lh[i] = 0;
    __syncthreads();
    if (bid < NBR) {
        int beg = bid * PER_R, end = min(beg + PER_R, 2 * EREG);
        for (int i = beg + t; i < end; i += 1024) {
            int d = (i < EREG) ? dR1[i] : NMRNA + dR2[i - EREG];
            atomicAdd(&lh[d], 1);      // LDS atomic
        }
        __syncthreads();
        int* out = histR + (size_t)bid * NG;
        for (int i = t; i < NG; i += 1024) out[i] = lh[i];
    } else {
        int pb = bid - NBR;
        int beg = pb * PER_P, end = min(beg + PER_P, EPM + EPI);
        for (int i = beg + t; i < end; i += 1024) {
            int g = (i < EPM) ? sP1[i] : NMRNA + sP2[i - EPM];
            atomicAdd(&lh[g], 1);      // LDS atomic
        }
        __syncthreads();
        int* out = histP + (size_t)pb * NG;
        for (int i = t; i < NG; i += 1024) out[i] = lh[i];
    }
}

// Block 0: reg space; block 1: pat space. Produces rowptr[NG+1] and per-chunk bases.
__global__ __launch_bounds__(1024) void k_scan(
        const int* __restrict__ histR, const int* __restrict__ histP,
        int* __restrict__ rowptrR, int* __restrict__ baseR,
        int* __restrict__ rowptrP, int* __restrict__ baseP) {
    __shared__ int part[1024];
    int isP = blockIdx.x;
    const int* hist = isP ? histP : histR;
    int nb = isP ? NBP : NBR;
    int* rowptr = isP ? rowptrP : rowptrR;
    int* base = isP ? baseP : baseR;
    int t = threadIdx.x;
    const int chunk = (NG + 1023) >> 10;   // 22
    int beg = t * chunk, end = min(beg + chunk, NG);
    int s = 0;
    for (int i = beg; i < end; i++) {
        int c = 0;
        for (int b = 0; b < nb; b++) c += hist[(size_t)b * NG + i];
        s += c;
    }
    part[t] = s;
    __syncthreads();
    for (int st = 1; st < 1024; st <<= 1) {
        int v = (t >= st) ? part[t - st] : 0;
        __syncthreads();
        part[t] += v;
        __syncthreads();
    }
    int off = part[t] - s;   // exclusive prefix
    for (int i = beg; i < end; i++) {
        rowptr[i] = off;
        int acc = off;
        for (int b = 0; b < nb; b++) {
            base[(size_t)b * NG + i] = acc;
            acc += hist[(size_t)b * NG + i];
        }
        off = acc;
    }
    if (end == NG) rowptr[NG] = off;
}

// Same chunking as k_hist; LDS cursors from base; rank via LDS atomic; plain stores.
__global__ __launch_bounds__(1024) void k_place(
        const int* __restrict__ sR1, const int* __restrict__ dR1, const float* __restrict__ wR1,
        const int* __restrict__ sR2, const int* __restrict__ dR2, const float* __restrict__ wR2,
        const int* __restrict__ sP1, const int* __restrict__ dP1, const float* __restrict__ wP1,
        const int* __restrict__ sP2, const int* __restrict__ dP2, const float* __restrict__ wP2,
        const int* __restrict__ baseR, const int* __restrict__ baseP,
        int2* __restrict__ epR, int2* __restrict__ epP) {
    __shared__ int lcur[NG];
    int t = threadIdx.x, bid = blockIdx.x;
    if (bid < NBR) {
        const int* base = baseR + (size_t)bid * NG;
        for (int i = t; i < NG; i += 1024) lcur[i] = base[i];
        __syncthreads();
        int beg = bid * PER_R, end = min(beg + PER_R, 2 * EREG);
        for (int i = beg + t; i < end; i += 1024) {
            int d, s; float w;
            if (i < EREG) { d = dR1[i]; s = sR1[i]; w = wR1[i]; }
            else { int k = i - EREG; d = NMRNA + dR2[k]; s = sR2[k]; w = wR2[k]; }
            int p = atomicAdd(&lcur[d], 1);    // LDS atomic -> rank
            int2 e; e.x = s; e.y = __float_as_int(w);
            epR[p] = e;                        // plain scattered 8B store
        }
    } else {
        int pb = bid - NBR;
        const int* base = baseP + (size_t)pb * NG;
        for (int i = t; i < NG; i += 1024) lcur[i] = base[i];
        __syncthreads();
        int beg = pb * PER_P, end = min(beg + PER_P, EPM + EPI);
        for (int i = beg + t; i < end; i += 1024) {
            int g, b; float w;
            if (i < EPM) { g = sP1[i]; b = dP1[i]; w = wP1[i]; }
            else { int k = i - EPM; g = NMRNA + sP2[k]; b = dP2[k]; w = wP2[k]; }
            int p = atomicAdd(&lcur[g], 1);
            int2 e; e.x = (g << 4) | b; e.y = __float_as_int(w);
            epP[p] = e;
        }
    }
}

// ---------- masked patch pooling: 2048 blocks ----------
#define PSLICES 128
#define PCHUNK (NP / PSLICES)   // 16
__global__ __launch_bounds__(256) void k_pool(
        const float* __restrict__ patches, const float* __restrict__ mask,
        float* __restrict__ pooled, float* __restrict__ masksum) {
    int b = blockIdx.y;
    int p0 = blockIdx.x * PCHUNK;
    int t = threadIdx.x;  // 256 threads x float4 = 1024 = PD
    float4 acc = {0.f, 0.f, 0.f, 0.f};
    float msum = 0.f;
#pragma unroll
    for (int pp = 0; pp < PCHUNK; pp++) {
        int p = p0 + pp;
        float m = mask[b * NP + p];  // uniform -> s_load
        float4 v = ((const float4*)(patches + ((size_t)b * NP + p) * PD))[t];
        msum += m;
        acc.x += m * v.x; acc.y += m * v.y; acc.z += m * v.z; acc.w += m * v.w;
    }
    float* op = pooled + (size_t)b * PD + t * 4;
    atomicAdd(op + 0, acc.x);
    atomicAdd(op + 1, acc.y);
    atomicAdd(op + 2, acc.z);
    atomicAdd(op + 3, acc.w);
    if (t == 0) atomicAdd(&masksum[b], msum);
}

// ---------- CSR gather from bf16 emb, unified rowptr, unroll-4 ----------
__global__ __launch_bounds__(256) void k_gather2(
        const unsigned short* __restrict__ embB_mir, const unsigned short* __restrict__ embB_mrna,
        const int* __restrict__ rowptrR, const int2* __restrict__ epR,
        unsigned short* __restrict__ agg) {
    __shared__ float lacc[4][HID];
    int n = blockIdx.x;
    const unsigned short* emb = (n < NMRNA) ? embB_mir : embB_mrna;
    int wv = threadIdx.x >> 6, l = threadIdx.x & 63;
    int beg = rowptrR[n], end = rowptrR[n + 1];
    float a0 = 0.f, a1 = 0.f, a2 = 0.f, a3 = 0.f;
    float c0 = 0.f, c1 = 0.f, c2 = 0.f, c3 = 0.f;
    float d0 = 0.f, d1 = 0.f, d2 = 0.f, d3 = 0.f;
    float g0 = 0.f, g1 = 0.f, g2 = 0.f, g3 = 0.f;
    int j = beg + wv;
    for (; j + 12 < end; j += 16) {
        int2 e0 = epR[j];             // wave-uniform -> s_load_dwordx2
        int2 e1 = epR[j + 4];
        int2 e2 = epR[j + 8];
        int2 e3 = epR[j + 12];
        float w0 = __int_as_float(e0.y), w1 = __int_as_float(e1.y);
        float w2 = __int_as_float(e2.y), w3 = __int_as_float(e3.y);
        ushort4 v0 = *(const ushort4*)(emb + (size_t)e0.x * HID + l * 4);
        ushort4 v1 = *(const ushort4*)(emb + (size_t)e1.x * HID + l * 4);
        ushort4 v2 = *(const ushort4*)(emb + (size_t)e2.x * HID + l * 4);
        ushort4 v3 = *(const ushort4*)(emb + (size_t)e3.x * HID + l * 4);
        a0 += w0 * b2f(v0.x); a1 += w0 * b2f(v0.y); a2 += w0 * b2f(v0.z); a3 += w0 * b2f(v0.w);
        c0 += w1 * b2f(v1.x); c1 += w1 * b2f(v1.y); c2 += w1 * b2f(v1.z); c3 += w1 * b2f(v1.w);
        d0 += w2 * b2f(v2.x); d1 += w2 * b2f(v2.y); d2 += w2 * b2f(v2.z); d3 += w2 * b2f(v2.w);
        g0 += w3 * b2f(v3.x); g1 += w3 * b2f(v3.y); g2 += w3 * b2f(v3.z); g3 += w3 * b2f(v3.w);
    }
    for (; j < end; j += 4) {
        int2 e0 = epR[j];
        float w0 = __int_as_float(e0.y);
        ushort4 v0 = *(const ushort4*)(emb + (size_t)e0.x * HID + l * 4);
        a0 += w0 * b2f(v0.x); a1 += w0 * b2f(v0.y); a2 += w0 * b2f(v0.z); a3 += w0 * b2f(v0.w);
    }
    float4 st = { a0 + c0 + d0 + g0, a1 + c1 + d1 + g1,
                  a2 + c2 + d2 + g2, a3 + c3 + d3 + g3 };
    ((float4*)lacc[wv])[l] = st;
    __syncthreads();
    int c = threadIdx.x;
    agg[(size_t)n * HID + c] = f2b(lacc[0][c] + lacc[1][c] + lacc[2][c] + lacc[3][c]);
}

// ---------- MFMA node update + fused patient readout (pat weights from sorted CSR) ----------
__global__ __launch_bounds__(256) void k_update2(
        const unsigned short* __restrict__ A,
        const float* __restrict__ emb_mrna, const float* __restrict__ emb_mirna,
        const unsigned short* __restrict__ wb,
        const float* __restrict__ bias_mrna, const float* __restrict__ bias_mirna,
        const int* __restrict__ rowptrP, const int2* __restrict__ epP,
        float* __restrict__ acc_pat) {
    __shared__ float ht[16][HID + 1];
    __shared__ float wtile[16][BB];
    int row0 = blockIdx.x * 16;   // global row (NG space); NMRNA % 16 == 0, never straddles
    const float* emb; const unsigned short* Wb; const float* bias; int base;
    if (row0 < NMRNA) { emb = emb_mrna;  Wb = wb;             bias = bias_mrna;  base = 0; }
    else              { emb = emb_mirna; Wb = wb + HID * HID; bias = bias_mirna; base = NMRNA; }
    int tid = threadIdx.x;
    if (tid < 16 * BB) wtile[tid >> 4][tid & 15] = 0.f;
    __syncthreads();
    // build 16x16 pat weight tile from sorted pat-edge segments (LDS atomics, ~256 edges)
    int pbeg = rowptrP[row0], pend = rowptrP[row0 + 16];
    for (int j = pbeg + tid; j < pend; j += 256) {
        int2 e = epP[j];
        atomicAdd(&wtile[(e.x >> 4) - row0][e.x & 15], __int_as_float(e.y));
    }
    int wv = tid >> 6;
    int lane = tid & 63;
    int m = lane & 15;   // A row offset / D col offset
    int q = lane >> 4;   // quad: k = q*8 + j
    bf16x8 afrag[8];
    const unsigned short* arow = A + (size_t)(row0 + m) * HID + q * 8;
#pragma unroll
    for (int kk = 0; kk < 8; kk++)
        afrag[kk] = *(const bf16x8*)(arow + kk * 32);
    f32x4 acc[4];
#pragma unroll
    for (int t = 0; t < 4; t++) acc[t] = (f32x4){0.f, 0.f, 0.f, 0.f};
    int col_base = wv * 64;
#pragma unroll
    for (int t = 0; t < 4; t++) {
        const unsigned short* brow = Wb + (size_t)(col_base + t * 16 + m) * HID + q * 8;
#pragma unroll
        for (int kk = 0; kk < 8; kk++) {
            bf16x8 bfrag = *(const bf16x8*)(brow + kk * 32);
            acc[t] = __builtin_amdgcn_mfma_f32_16x16x32_bf16(afrag[kk], bfrag, acc[t], 0, 0, 0);
        }
    }
#pragma unroll
    for (int t = 0; t < 4; t++) {
        int col = col_base + t * 16 + m;
        float bv = bias[col];
#pragma unroll
        for (int r = 0; r < 4; r++) {
            int lrow = q * 4 + r;                                // local row 0..15
            size_t idxe = (size_t)(row0 - base + lrow) * HID + col;
            ht[lrow][col] = emb[idxe] + gelu_exact(acc[t][r] + bv);
        }
    }
    __syncthreads();
    // fused skinny matmul: per col c, 16 patients x 16 rows
    int c = tid;
    float hv[16];
#pragma unroll
    for (int r = 0; r < 16; r++) hv[r] = ht[r][c];
#pragma unroll
    for (int b = 0; b < BB; b++) {
        float s = 0.f;
#pragma unroll
        for (int r = 0; r < 16; r++) s += wtile[r][b] * hv[r];   // LDS broadcast
        atomicAdd(&acc_pat[b * HID + c], s);                     // coalesced atomics
    }
}

// ================= head chain, column-parallel =================
__global__ __launch_bounds__(256) void k_head_a(
        const float* __restrict__ acc_pat, const float* __restrict__ pooled,
        const float* __restrict__ masksum,
        const float* __restrict__ proj_w, const float* __restrict__ proj_b,
        const float* __restrict__ wsi_w, const float* __restrict__ wsi_b,
        float* __restrict__ pg, float* __restrict__ wt) {
    __shared__ float red[256];
    int c = blockIdx.x;
    int t = threadIdx.x;
    int b = t & 15, kk = t >> 4;

    const float* wr = proj_w + (size_t)c * HID + kk * 16;
    const float* xr = acc_pat + (size_t)b * HID + kk * 16;
    float s = 0.f;
#pragma unroll
    for (int i = 0; i < 16; i += 4) {
        float4 w4 = *(const float4*)(wr + i);
        float4 x4 = *(const float4*)(xr + i);
        s += x4.x * w4.x + x4.y * w4.y + x4.z * w4.z + x4.w * w4.w;
    }
    float tot = kred(s, red, b, kk);
    if (kk == 0) pg[(size_t)b * HID + c] = gelu_exact(tot + proj_b[c]);

    const float* wr2 = wsi_w + (size_t)c * PD + kk * 64;
    const float* xr2 = pooled + (size_t)b * PD + kk * 64;
    float s2 = 0.f;
#pragma unroll
    for (int i = 0; i < 64; i += 4) {
        float4 w4 = *(const float4*)(wr2 + i);
        float4 x4 = *(const float4*)(xr2 + i);
        s2 += x4.x * w4.x + x4.y * w4.y + x4.z * w4.z + x4.w * w4.w;
    }
    float tot2 = kred(s2, red, b, kk);
    if (kk == 0) {
        float sm = masksum[b];
        float denom = fmaxf(sm, 1.0f);
        wt[(size_t)b * HID + c] = gelu_exact(tot2 / denom + wsi_b[c] * (sm / denom));
    }
}

__global__ __launch_bounds__(256) void k_head_b(
        const float* __restrict__ wt,
        const float* __restrict__ mlp_w, const float* __restrict__ mlp_b,
        float* __restrict__ ml) {
    __shared__ float red[256];
    int c = blockIdx.x;
    int t = threadIdx.x;
    int b = t & 15, kk = t >> 4;
    const float* wr = mlp_w + (size_t)c * HID + kk * 16;
    const float* xr = wt + (size_t)b * HID + kk * 16;
    float s = 0.f;
#pragma unroll
    for (int i = 0; i < 16; i += 4) {
        float4 w4 = *(const float4*)(wr + i);
        float4 x4 = *(const float4*)(xr + i);
        s += x4.x * w4.x + x4.y * w4.y + x4.z * w4.z + x4.w * w4.w;
    }
    float tot = kred(s, red, b, kk);
    if (kk == 0) ml[(size_t)b * HID + c] = gelu_exact(tot + mlp_b[c]);
}

__global__ __launch_bounds__(256) void k_head_c(
        const float* __restrict__ pg, const float* __restrict__ ml,
        const float* __restrict__ ln_g, const float* __restrict__ ln_b,
        const float* __restrict__ wln_g, const float* __restrict__ wln_b,
        const float* __restrict__ omics_w, const float* __restrict__ omics_b,
        const float* __restrict__ fuse_b2,
        float* __restrict__ vecbuf, float* __restrict__ out_omics,
        float* __restrict__ out_fused) {
    __shared__ float red[256];
    int b = blockIdx.x, c = threadIdx.x;
    if (c < NBINS) out_fused[b * NBINS + c] = fuse_b2[c];
    float g = pg[(size_t)b * HID + c];
    float mean = block_reduce_sum(g, red) * (1.0f / HID);
    float d = g - mean;
    float var = block_reduce_sum(d * d, red) * (1.0f / HID);
    float patv = d * rsqrtf(var + 1e-5f) * ln_g[c] + ln_b[c];
    vecbuf[(size_t)b * (2 * HID) + c] = patv;
    for (int o = 0; o < NBINS; o++) {
        float r = block_reduce_sum(patv * omics_w[o * HID + c], red);
        if (c == 0) out_omics[b * NBINS + o] = r + omics_b[o];
    }
    float m = ml[(size_t)b * HID + c];
    mean = block_reduce_sum(m, red) * (1.0f / HID);
    d = m - mean;
    var = block_reduce_sum(d * d, red) * (1.0f / HID);
    vecbuf[(size_t)b * (2 * HID) + HID + c] = d * rsqrtf(var + 1e-5f) * wln_g[c] + wln_b[c];
}

__global__ __launch_bounds__(256) void k_head_d(
        const float* __restrict__ vecbuf,
        const float* __restrict__ fuse_w1, const float* __restrict__ fuse_b1,
        const float* __restrict__ fuse_w2,
        float* __restrict__ out_fused) {
    __shared__ float red[256];
    int c = blockIdx.x;
    int t = threadIdx.x;
    int b = t & 15, kk = t >> 4;
    const float* wr = fuse_w1 + (size_t)c * (2 * HID) + kk * 32;
    const float* xr = vecbuf + (size_t)b * (2 * HID) + kk * 32;
    float s = 0.f;
#pragma unroll
    for (int i = 0; i < 32; i += 4) {
        float4 w4 = *(const float4*)(wr + i);
        float4 x4 = *(const float4*)(xr + i);
        s += x4.x * w4.x + x4.y * w4.y + x4.z * w4.z + x4.w * w4.w;
    }
    float tot = kred(s, red, b, kk);
    if (kk == 0) {
        float h1 = gelu_exact(tot + fuse_b1[c]);
#pragma unroll
        for (int o = 0; o < NBINS; o++)
            atomicAdd(&out_fused[b * NBINS + o], h1 * fuse_w2[o * HID + c]);
    }
}

extern "C" void kernel_launch(void* const* d_in, const int* in_sizes, int n_in,
                              void* d_out, int out_size, void* d_ws, size_t ws_size,
                              hipStream_t stream) {
    const float* emb_mirna  = (const float*)d_in[0];
    const float* emb_mrna   = (const float*)d_in[1];
    const float* w_mir2mrna = (const float*)d_in[2];
    const float* w_mrna2mir = (const float*)d_in[3];
    const float* w_mrna2pat = (const float*)d_in[4];
    const float* w_mir2pat  = (const float*)d_in[5];
    const float* reg_w_mrna = (const float*)d_in[6];
    const float* reg_b_mrna = (const float*)d_in[7];
    const float* reg_w_mirna= (const float*)d_in[8];
    const float* reg_b_mirna= (const float*)d_in[9];
    const float* proj_w     = (const float*)d_in[10];
    const float* proj_b     = (const float*)d_in[11];
    const float* ln_g       = (const float*)d_in[12];
    const float* ln_b       = (const float*)d_in[13];
    const float* omics_w    = (const float*)d_in[14];
    const float* omics_b    = (const float*)d_in[15];
    const float* wsi_w      = (const float*)d_in[16];
    const float* wsi_b      = (const float*)d_in[17];
    const float* mlp_w      = (const float*)d_in[18];
    const float* mlp_b      = (const float*)d_in[19];
    const float* wln_g      = (const float*)d_in[20];
    const float* wln_b      = (const float*)d_in[21];
    const float* fuse_w1    = (const float*)d_in[22];
    const float* fuse_b1    = (const float*)d_in[23];
    const float* fuse_w2    = (const float*)d_in[24];
    const float* fuse_b2    = (const float*)d_in[25];
    const float* patches    = (const float*)d_in[26];
    const float* mask       = (const float*)d_in[27];
    const int* src_m2M = (const int*)d_in[28];
    const int* dst_m2M = (const int*)d_in[29];
    const int* src_M2m = (const int*)d_in[30];
    const int* dst_M2m = (const int*)d_in[31];
    const int* src_M2p = (const int*)d_in[32];
    const int* dst_M2p = (const int*)d_in[33];
    const int* src_m2p = (const int*)d_in[34];
    const int* dst_m2p = (const int*)d_in[35];

    float* ws = (float*)d_ws;
    // ---- zeroed region (tiny now: no Wp, no cnt) ----
    size_t off = 0;
    float* acc_pat  = ws + off; off += (size_t)BB * HID;       // 4096
    float* pooled   = ws + off; off += (size_t)BB * PD;        // 16384
    float* masksum  = ws + off; off += BB;                     // 16
    size_t zero_floats = off;                                  // 20496 floats, %4==0
    // ---- non-zeroed region ----
    unsigned short* agg_bf = (unsigned short*)(ws + off); off += (size_t)NG * HID / 2;
    unsigned short* wb     = (unsigned short*)(ws + off); off += (size_t)2 * HID * HID / 2;
    unsigned short* embB_mir  = (unsigned short*)(ws + off); off += (size_t)NMIR * HID / 2;
    unsigned short* embB_mrna = (unsigned short*)(ws + off); off += (size_t)NMRNA * HID / 2;
    float* pg       = ws + off; off += (size_t)BB * HID;
    float* wt       = ws + off; off += (size_t)BB * HID;
    float* ml       = ws + off; off += (size_t)BB * HID;
    float* vecbuf   = ws + off; off += (size_t)BB * 2 * HID;
    int* histR      = (int*)(ws + off); off += (size_t)NBR * NG;
    int* histP      = (int*)(ws + off); off += (size_t)NBP * NG;
    int* baseR      = (int*)(ws + off); off += (size_t)NBR * NG;
    int* baseP      = (int*)(ws + off); off += (size_t)NBP * NG;
    int* rowptrR    = (int*)(ws + off); off += NG + 2;
    int* rowptrP    = (int*)(ws + off); off += NG + 2;
    int2* epR       = (int2*)(ws + off); off += (size_t)2 * (2 * EREG);
    int2* epP       = (int2*)(ws + off); off += (size_t)2 * (EPM + EPI);

    float* out_fused = (float*)d_out;               // [16,4]
    float* out_omics = (float*)d_out + BB * NBINS;  // [16,4]

    hipMemsetAsync(d_ws, 0, zero_floats * sizeof(float), stream);

    // 1. conversions (streaming, no atomics)
    k_cvt<<<CVT_TOTAL, 256, 0, stream>>>(
        emb_mirna, emb_mrna, embB_mir, embB_mrna,
        reg_w_mrna, reg_w_mirna, wb);

    // 2-4. counting-sort CSR build (reg by dst, pat by src) — zero global atomics
    k_hist<<<NBR + NBP, 1024, 0, stream>>>(
        dst_m2M, dst_M2m, src_M2p, src_m2p, histR, histP);
    k_scan<<<2, 1024, 0, stream>>>(histR, histP, rowptrR, baseR, rowptrP, baseP);
    k_place<<<NBR + NBP, 1024, 0, stream>>>(
        src_m2M, dst_m2M, w_mir2mrna, src_M2m, dst_M2m, w_mrna2mir,
        src_M2p, dst_M2p, w_mrna2pat, src_m2p, dst_m2p, w_mir2pat,
        baseR, baseP, epR, epP);

    // 5. wsi masked pooling
    k_pool<<<dim3(PSLICES, BB), 256, 0, stream>>>(patches, mask, pooled, masksum);

    // 6. CSR gather from bf16 embeddings
    k_gather2<<<NG, 256, 0, stream>>>(embB_mir, embB_mrna, rowptrR, epR, agg_bf);

    // 7. MFMA node update + fused patient readout (pat weights from sorted epP)
    k_update2<<<NG / 16, 256, 0, stream>>>(agg_bf, emb_mrna, emb_mirna, wb,
                                           reg_b_mrna, reg_b_mirna,
                                           rowptrP, epP, acc_pat);

    // 8-11. head chain, column-parallel
    k_head_a<<<HID, 256, 0, stream>>>(acc_pat, pooled, masksum,
                                      proj_w, proj_b, wsi_w, wsi_b, pg, wt);
    k_head_b<<<HID, 256, 0, stream>>>(wt, mlp_w, mlp_b, ml);
    k_head_c<<<BB, 256, 0, stream>>>(pg, ml, ln_g, ln_b, wln_g, wln_b,
                                     omics_w, omics_b, fuse_b2,
                                     vecbuf, out_omics, out_fused);
    k_head_d<<<HID, 256, 0, stream>>>(vecbuf, fuse_w1, fuse_b1, fuse_w2, out_fused);
}

// Round 7
// 597.509 us; speedup vs baseline: 1.6663x; 1.6663x over previous
//
#include <hip/hip_runtime.h>
#include <math.h>

#define HID 256
#define NBINS 4
#define NMIR 2000
#define NMRNA 20000
#define NG (NMRNA + NMIR)   // 22000 union gene space
#define BB 16
#define NP 2048
#define PD 1024
#define EREG 300000
#define EPM 320000
#define EPI 32000

typedef __attribute__((ext_vector_type(8))) short bf16x8;
typedef __attribute__((ext_vector_type(4))) float f32x4;

__device__ __forceinline__ float gelu_exact(float x) {
    return 0.5f * x * (1.0f + erff(x * 0.7071067811865475f));
}

// fp32 -> bf16 round-to-nearest-even (bits)
__device__ __forceinline__ unsigned short f2b(float f) {
    union { float f; unsigned int u; } v; v.f = f;
    unsigned int u = v.u + 0x7fffu + ((v.u >> 16) & 1u);
    return (unsigned short)(u >> 16);
}

__device__ __forceinline__ float b2f(unsigned short u) {
    union { unsigned int i; float f; } v; v.i = ((unsigned int)u) << 16;
    return v.f;
}

// blockDim.x == 256 assumed
__device__ __forceinline__ float block_reduce_sum(float v, float* red) {
    int c = threadIdx.x;
    red[c] = v;
    __syncthreads();
    for (int st = 128; st > 0; st >>= 1) {
        if (c < st) red[c] += red[c + st];
        __syncthreads();
    }
    float r = red[0];
    __syncthreads();
    return r;
}

// 256-thread block laid out as (b = t&15, kk = t>>4); reduce over kk, result to all
__device__ __forceinline__ float kred(float v, float* red, int b, int kk) {
    red[kk * 16 + b] = v;
    __syncthreads();
    for (int st = 8; st >= 1; st >>= 1) {
        if (kk < st) red[kk * 16 + b] += red[(kk + st) * 16 + b];
        __syncthreads();
    }
    float r = red[b];
    __syncthreads();
    return r;
}

// ================= conversions: emb->bf16 + reg weights->bf16 =================
#define CVT_EMB ((NG * HID) / 4096)              // 1375 blocks, 16 elems/thread
#define CVT_F2B ((2 * HID * HID) / 4096)         // 32
#define CVT_TOTAL (CVT_EMB + CVT_F2B)

__global__ __launch_bounds__(256) void k_cvt(
        const float* __restrict__ emb_mirna, const float* __restrict__ emb_mrna,
        unsigned short* __restrict__ embB_mir, unsigned short* __restrict__ embB_mrna,
        const float* __restrict__ regwA, const float* __restrict__ regwB,
        unsigned short* __restrict__ wb) {
    int bid = blockIdx.x;
    int t = threadIdx.x;
    if (bid < CVT_EMB) {
        const size_t NM = (size_t)NMIR * HID;  // 512000; 4096-block boundary aligned (125*4096)
        float4 v[4];
#pragma unroll
        for (int k = 0; k < 4; k++) {
            size_t e = (size_t)bid * 4096 + k * 1024 + t * 4;
            v[k] = (e < NM) ? *(const float4*)(emb_mirna + e)
                            : *(const float4*)(emb_mrna + (e - NM));
        }
#pragma unroll
        for (int k = 0; k < 4; k++) {
            size_t e = (size_t)bid * 4096 + k * 1024 + t * 4;
            ushort4 u = { f2b(v[k].x), f2b(v[k].y), f2b(v[k].z), f2b(v[k].w) };
            if (e < NM) *(ushort4*)(embB_mir + e) = u;
            else        *(ushort4*)(embB_mrna + (e - NM)) = u;
        }
        return;
    }
    bid -= CVT_EMB;
    {
        const size_t NW = (size_t)HID * HID;   // 65536; aligned at block 16
        float4 v[4];
#pragma unroll
        for (int k = 0; k < 4; k++) {
            size_t e = (size_t)bid * 4096 + k * 1024 + t * 4;
            v[k] = (e < NW) ? *(const float4*)(regwA + e)
                            : *(const float4*)(regwB + (e - NW));
        }
#pragma unroll
        for (int k = 0; k < 4; k++) {
            size_t e = (size_t)bid * 4096 + k * 1024 + t * 4;
            ushort4 u = { f2b(v[k].x), f2b(v[k].y), f2b(v[k].z), f2b(v[k].w) };
            *(ushort4*)(wb + e) = u;
        }
    }
}

// ================= counting-sort CSR build: ZERO global atomics =================
#define NBR 16
#define NBP 8
#define PER_R ((2 * EREG + NBR - 1) / NBR)   // 37500
#define PER_P ((EPM + EPI + NBP - 1) / NBP)  // 44000

__global__ __launch_bounds__(1024) void k_hist(
        const int* __restrict__ dR1, const int* __restrict__ dR2,
        const int* __restrict__ sP1, const int* __restrict__ sP2,
        int* __restrict__ histR, int* __restrict__ histP) {
    __shared__ int lh[NG];
    int t = threadIdx.x, bid = blockIdx.x;
    for (int i = t; i < NG; i += 1024) lh[i] = 0;
    __syncthreads();
    if (bid < NBR) {
        int beg = bid * PER_R, end = min(beg + PER_R, 2 * EREG);
        for (int i = beg + t; i < end; i += 1024) {
            int d = (i < EREG) ? dR1[i] : NMRNA + dR2[i - EREG];
            atomicAdd(&lh[d], 1);      // LDS atomic
        }
        __syncthreads();
        int* out = histR + (size_t)bid * NG;
        for (int i = t; i < NG; i += 1024) out[i] = lh[i];
    } else {
        int pb = bid - NBR;
        int beg = pb * PER_P, end = min(beg + PER_P, EPM + EPI);
        for (int i = beg + t; i < end; i += 1024) {
            int g = (i < EPM) ? sP1[i] : NMRNA + sP2[i - EPM];
            atomicAdd(&lh[g], 1);      // LDS atomic
        }
        __syncthreads();
        int* out = histP + (size_t)pb * NG;
        for (int i = t; i < NG; i += 1024) out[i] = lh[i];
    }
}

// ---- per-gene running sum over chunks (coalesced): baseRel + cnt ----
#define CS_B ((NG + 255) / 256)   // 86 blocks per space
__global__ __launch_bounds__(256) void k_colsum(
        const int* __restrict__ histR, const int* __restrict__ histP,
        int* __restrict__ baseR, int* __restrict__ baseP,
        int* __restrict__ cntR, int* __restrict__ cntP) {
    int bid = blockIdx.x;
    if (bid < CS_B) {
        int i = bid * 256 + threadIdx.x;
        if (i >= NG) return;
        int run = 0;
#pragma unroll
        for (int b = 0; b < NBR; b++) {
            baseR[(size_t)b * NG + i] = run;      // relative base
            run += histR[(size_t)b * NG + i];
        }
        cntR[i] = run;
    } else {
        int i = (bid - CS_B) * 256 + threadIdx.x;
        if (i >= NG) return;
        int run = 0;
#pragma unroll
        for (int b = 0; b < NBP; b++) {
            baseP[(size_t)b * NG + i] = run;
            run += histP[(size_t)b * NG + i];
        }
        cntP[i] = run;
    }
}

// ---- scan over cnt only (the proven round-2..5 shape) ----
__global__ __launch_bounds__(1024) void k_scan_small(
        const int* __restrict__ cntR, const int* __restrict__ cntP,
        int* __restrict__ rowptrR, int* __restrict__ rowptrP) {
    __shared__ int part[1024];
    const int* cnt = blockIdx.x ? cntP : cntR;
    int* rowptr = blockIdx.x ? rowptrP : rowptrR;
    int t = threadIdx.x;
    const int chunk = (NG + 1023) >> 10;   // 22
    int beg = t * chunk, end = min(beg + chunk, NG);
    int s = 0;
    for (int i = beg; i < end; i++) s += cnt[i];
    part[t] = s;
    __syncthreads();
    for (int st = 1; st < 1024; st <<= 1) {
        int v = (t >= st) ? part[t - st] : 0;
        __syncthreads();
        part[t] += v;
        __syncthreads();
    }
    int off = part[t] - s;   // exclusive prefix
    for (int i = beg; i < end; i++) {
        rowptr[i] = off;
        off += cnt[i];
    }
    if (end == NG) rowptr[NG] = off;
}

// Same chunking as k_hist; LDS cursors = rowptr + baseRel; rank via LDS atomic; plain stores.
__global__ __launch_bounds__(1024) void k_place(
        const int* __restrict__ sR1, const int* __restrict__ dR1, const float* __restrict__ wR1,
        const int* __restrict__ sR2, const int* __restrict__ dR2, const float* __restrict__ wR2,
        const int* __restrict__ sP1, const int* __restrict__ dP1, const float* __restrict__ wP1,
        const int* __restrict__ sP2, const int* __restrict__ dP2, const float* __restrict__ wP2,
        const int* __restrict__ baseR, const int* __restrict__ baseP,
        const int* __restrict__ rowptrR, const int* __restrict__ rowptrP,
        int2* __restrict__ epR, int2* __restrict__ epP) {
    __shared__ int lcur[NG];
    int t = threadIdx.x, bid = blockIdx.x;
    if (bid < NBR) {
        const int* base = baseR + (size_t)bid * NG;
        for (int i = t; i < NG; i += 1024) lcur[i] = rowptrR[i] + base[i];
        __syncthreads();
        int beg = bid * PER_R, end = min(beg + PER_R, 2 * EREG);
        for (int i = beg + t; i < end; i += 1024) {
            int d, s; float w;
            if (i < EREG) { d = dR1[i]; s = sR1[i]; w = wR1[i]; }
            else { int k = i - EREG; d = NMRNA + dR2[k]; s = sR2[k]; w = wR2[k]; }
            int p = atomicAdd(&lcur[d], 1);    // LDS atomic -> rank
            int2 e; e.x = s; e.y = __float_as_int(w);
            epR[p] = e;                        // plain scattered 8B store
        }
    } else {
        int pb = bid - NBR;
        const int* base = baseP + (size_t)pb * NG;
        for (int i = t; i < NG; i += 1024) lcur[i] = rowptrP[i] + base[i];
        __syncthreads();
        int beg = pb * PER_P, end = min(beg + PER_P, EPM + EPI);
        for (int i = beg + t; i < end; i += 1024) {
            int g, b; float w;
            if (i < EPM) { g = sP1[i]; b = dP1[i]; w = wP1[i]; }
            else { int k = i - EPM; g = NMRNA + sP2[k]; b = dP2[k]; w = wP2[k]; }
            int p = atomicAdd(&lcur[g], 1);
            int2 e; e.x = (g << 4) | b; e.y = __float_as_int(w);
            epP[p] = e;
        }
    }
}

// ---------- masked patch pooling: 2048 blocks ----------
#define PSLICES 128
#define PCHUNK (NP / PSLICES)   // 16
__global__ __launch_bounds__(256) void k_pool(
        const float* __restrict__ patches, const float* __restrict__ mask,
        float* __restrict__ pooled, float* __restrict__ masksum) {
    int b = blockIdx.y;
    int p0 = blockIdx.x * PCHUNK;
    int t = threadIdx.x;  // 256 threads x float4 = 1024 = PD
    float4 acc = {0.f, 0.f, 0.f, 0.f};
    float msum = 0.f;
#pragma unroll
    for (int pp = 0; pp < PCHUNK; pp++) {
        int p = p0 + pp;
        float m = mask[b * NP + p];  // uniform -> s_load
        float4 v = ((const float4*)(patches + ((size_t)b * NP + p) * PD))[t];
        msum += m;
        acc.x += m * v.x; acc.y += m * v.y; acc.z += m * v.z; acc.w += m * v.w;
    }
    float* op = pooled + (size_t)b * PD + t * 4;
    atomicAdd(op + 0, acc.x);
    atomicAdd(op + 1, acc.y);
    atomicAdd(op + 2, acc.z);
    atomicAdd(op + 3, acc.w);
    if (t == 0) atomicAdd(&masksum[b], msum);
}

// ---------- CSR gather from bf16 emb, unified rowptr, unroll-4 ----------
__global__ __launch_bounds__(256) void k_gather2(
        const unsigned short* __restrict__ embB_mir, const unsigned short* __restrict__ embB_mrna,
        const int* __restrict__ rowptrR, const int2* __restrict__ epR,
        unsigned short* __restrict__ agg) {
    __shared__ float lacc[4][HID];
    int n = blockIdx.x;
    const unsigned short* emb = (n < NMRNA) ? embB_mir : embB_mrna;
    int wv = threadIdx.x >> 6, l = threadIdx.x & 63;
    int beg = rowptrR[n], end = rowptrR[n + 1];
    float a0 = 0.f, a1 = 0.f, a2 = 0.f, a3 = 0.f;
    float c0 = 0.f, c1 = 0.f, c2 = 0.f, c3 = 0.f;
    float d0 = 0.f, d1 = 0.f, d2 = 0.f, d3 = 0.f;
    float g0 = 0.f, g1 = 0.f, g2 = 0.f, g3 = 0.f;
    int j = beg + wv;
    for (; j + 12 < end; j += 16) {
        int2 e0 = epR[j];             // wave-uniform -> s_load_dwordx2
        int2 e1 = epR[j + 4];
        int2 e2 = epR[j + 8];
        int2 e3 = epR[j + 12];
        float w0 = __int_as_float(e0.y), w1 = __int_as_float(e1.y);
        float w2 = __int_as_float(e2.y), w3 = __int_as_float(e3.y);
        ushort4 v0 = *(const ushort4*)(emb + (size_t)e0.x * HID + l * 4);
        ushort4 v1 = *(const ushort4*)(emb + (size_t)e1.x * HID + l * 4);
        ushort4 v2 = *(const ushort4*)(emb + (size_t)e2.x * HID + l * 4);
        ushort4 v3 = *(const ushort4*)(emb + (size_t)e3.x * HID + l * 4);
        a0 += w0 * b2f(v0.x); a1 += w0 * b2f(v0.y); a2 += w0 * b2f(v0.z); a3 += w0 * b2f(v0.w);
        c0 += w1 * b2f(v1.x); c1 += w1 * b2f(v1.y); c2 += w1 * b2f(v1.z); c3 += w1 * b2f(v1.w);
        d0 += w2 * b2f(v2.x); d1 += w2 * b2f(v2.y); d2 += w2 * b2f(v2.z); d3 += w2 * b2f(v2.w);
        g0 += w3 * b2f(v3.x); g1 += w3 * b2f(v3.y); g2 += w3 * b2f(v3.z); g3 += w3 * b2f(v3.w);
    }
    for (; j < end; j += 4) {
        int2 e0 = epR[j];
        float w0 = __int_as_float(e0.y);
        ushort4 v0 = *(const ushort4*)(emb + (size_t)e0.x * HID + l * 4);
        a0 += w0 * b2f(v0.x); a1 += w0 * b2f(v0.y); a2 += w0 * b2f(v0.z); a3 += w0 * b2f(v0.w);
    }
    float4 st = { a0 + c0 + d0 + g0, a1 + c1 + d1 + g1,
                  a2 + c2 + d2 + g2, a3 + c3 + d3 + g3 };
    ((float4*)lacc[wv])[l] = st;
    __syncthreads();
    int c = threadIdx.x;
    agg[(size_t)n * HID + c] = f2b(lacc[0][c] + lacc[1][c] + lacc[2][c] + lacc[3][c]);
}

// ---------- MFMA node update + fused patient readout (pat weights from sorted CSR) ----------
__global__ __launch_bounds__(256) void k_update2(
        const unsigned short* __restrict__ A,
        const float* __restrict__ emb_mrna, const float* __restrict__ emb_mirna,
        const unsigned short* __restrict__ wb,
        const float* __restrict__ bias_mrna, const float* __restrict__ bias_mirna,
        const int* __restrict__ rowptrP, const int2* __restrict__ epP,
        float* __restrict__ acc_pat) {
    __shared__ float ht[16][HID + 1];
    __shared__ float wtile[16][BB];
    int row0 = blockIdx.x * 16;   // global row (NG space); NMRNA % 16 == 0, never straddles
    const float* emb; const unsigned short* Wb; const float* bias; int base;
    if (row0 < NMRNA) { emb = emb_mrna;  Wb = wb;             bias = bias_mrna;  base = 0; }
    else              { emb = emb_mirna; Wb = wb + HID * HID; bias = bias_mirna; base = NMRNA; }
    int tid = threadIdx.x;
    if (tid < 16 * BB) wtile[tid >> 4][tid & 15] = 0.f;
    __syncthreads();
    // build 16x16 pat weight tile from sorted pat-edge segments (LDS atomics, ~256 edges)
    int pbeg = rowptrP[row0], pend = rowptrP[row0 + 16];
    for (int j = pbeg + tid; j < pend; j += 256) {
        int2 e = epP[j];
        atomicAdd(&wtile[(e.x >> 4) - row0][e.x & 15], __int_as_float(e.y));
    }
    int wv = tid >> 6;
    int lane = tid & 63;
    int m = lane & 15;   // A row offset / D col offset
    int q = lane >> 4;   // quad: k = q*8 + j
    bf16x8 afrag[8];
    const unsigned short* arow = A + (size_t)(row0 + m) * HID + q * 8;
#pragma unroll
    for (int kk = 0; kk < 8; kk++)
        afrag[kk] = *(const bf16x8*)(arow + kk * 32);
    f32x4 acc[4];
#pragma unroll
    for (int t = 0; t < 4; t++) acc[t] = (f32x4){0.f, 0.f, 0.f, 0.f};
    int col_base = wv * 64;
#pragma unroll
    for (int t = 0; t < 4; t++) {
        const unsigned short* brow = Wb + (size_t)(col_base + t * 16 + m) * HID + q * 8;
#pragma unroll
        for (int kk = 0; kk < 8; kk++) {
            bf16x8 bfrag = *(const bf16x8*)(brow + kk * 32);
            acc[t] = __builtin_amdgcn_mfma_f32_16x16x32_bf16(afrag[kk], bfrag, acc[t], 0, 0, 0);
        }
    }
#pragma unroll
    for (int t = 0; t < 4; t++) {
        int col = col_base + t * 16 + m;
        float bv = bias[col];
#pragma unroll
        for (int r = 0; r < 4; r++) {
            int lrow = q * 4 + r;                                // local row 0..15
            size_t idxe = (size_t)(row0 - base + lrow) * HID + col;
            ht[lrow][col] = emb[idxe] + gelu_exact(acc[t][r] + bv);
        }
    }
    __syncthreads();
    // fused skinny matmul: per col c, 16 patients x 16 rows
    int c = tid;
    float hv[16];
#pragma unroll
    for (int r = 0; r < 16; r++) hv[r] = ht[r][c];
#pragma unroll
    for (int b = 0; b < BB; b++) {
        float s = 0.f;
#pragma unroll
        for (int r = 0; r < 16; r++) s += wtile[r][b] * hv[r];   // LDS broadcast
        atomicAdd(&acc_pat[b * HID + c], s);                     // coalesced atomics
    }
}

// ================= head chain, column-parallel =================
__global__ __launch_bounds__(256) void k_head_a(
        const float* __restrict__ acc_pat, const float* __restrict__ pooled,
        const float* __restrict__ masksum,
        const float* __restrict__ proj_w, const float* __restrict__ proj_b,
        const float* __restrict__ wsi_w, const float* __restrict__ wsi_b,
        float* __restrict__ pg, float* __restrict__ wt) {
    __shared__ float red[256];
    int c = blockIdx.x;
    int t = threadIdx.x;
    int b = t & 15, kk = t >> 4;

    const float* wr = proj_w + (size_t)c * HID + kk * 16;
    const float* xr = acc_pat + (size_t)b * HID + kk * 16;
    float s = 0.f;
#pragma unroll
    for (int i = 0; i < 16; i += 4) {
        float4 w4 = *(const float4*)(wr + i);
        float4 x4 = *(const float4*)(xr + i);
        s += x4.x * w4.x + x4.y * w4.y + x4.z * w4.z + x4.w * w4.w;
    }
    float tot = kred(s, red, b, kk);
    if (kk == 0) pg[(size_t)b * HID + c] = gelu_exact(tot + proj_b[c]);

    const float* wr2 = wsi_w + (size_t)c * PD + kk * 64;
    const float* xr2 = pooled + (size_t)b * PD + kk * 64;
    float s2 = 0.f;
#pragma unroll
    for (int i = 0; i < 64; i += 4) {
        float4 w4 = *(const float4*)(wr2 + i);
        float4 x4 = *(const float4*)(xr2 + i);
        s2 += x4.x * w4.x + x4.y * w4.y + x4.z * w4.z + x4.w * w4.w;
    }
    float tot2 = kred(s2, red, b, kk);
    if (kk == 0) {
        float sm = masksum[b];
        float denom = fmaxf(sm, 1.0f);
        wt[(size_t)b * HID + c] = gelu_exact(tot2 / denom + wsi_b[c] * (sm / denom));
    }
}

__global__ __launch_bounds__(256) void k_head_b(
        const float* __restrict__ wt,
        const float* __restrict__ mlp_w, const float* __restrict__ mlp_b,
        float* __restrict__ ml) {
    __shared__ float red[256];
    int c = blockIdx.x;
    int t = threadIdx.x;
    int b = t & 15, kk = t >> 4;
    const float* wr = mlp_w + (size_t)c * HID + kk * 16;
    const float* xr = wt + (size_t)b * HID + kk * 16;
    float s = 0.f;
#pragma unroll
    for (int i = 0; i < 16; i += 4) {
        float4 w4 = *(const float4*)(wr + i);
        float4 x4 = *(const float4*)(xr + i);
        s += x4.x * w4.x + x4.y * w4.y + x4.z * w4.z + x4.w * w4.w;
    }
    float tot = kred(s, red, b, kk);
    if (kk == 0) ml[(size_t)b * HID + c] = gelu_exact(tot + mlp_b[c]);
}

__global__ __launch_bounds__(256) void k_head_c(
        const float* __restrict__ pg, const float* __restrict__ ml,
        const float* __restrict__ ln_g, const float* __restrict__ ln_b,
        const float* __restrict__ wln_g, const float* __restrict__ wln_b,
        const float* __restrict__ omics_w, const float* __restrict__ omics_b,
        const float* __restrict__ fuse_b2,
        float* __restrict__ vecbuf, float* __restrict__ out_omics,
        float* __restrict__ out_fused) {
    __shared__ float red[256];
    int b = blockIdx.x, c = threadIdx.x;
    if (c < NBINS) out_fused[b * NBINS + c] = fuse_b2[c];
    float g = pg[(size_t)b * HID + c];
    float mean = block_reduce_sum(g, red) * (1.0f / HID);
    float d = g - mean;
    float var = block_reduce_sum(d * d, red) * (1.0f / HID);
    float patv = d * rsqrtf(var + 1e-5f) * ln_g[c] + ln_b[c];
    vecbuf[(size_t)b * (2 * HID) + c] = patv;
    for (int o = 0; o < NBINS; o++) {
        float r = block_reduce_sum(patv * omics_w[o * HID + c], red);
        if (c == 0) out_omics[b * NBINS + o] = r + omics_b[o];
    }
    float m = ml[(size_t)b * HID + c];
    mean = block_reduce_sum(m, red) * (1.0f / HID);
    d = m - mean;
    var = block_reduce_sum(d * d, red) * (1.0f / HID);
    vecbuf[(size_t)b * (2 * HID) + HID + c] = d * rsqrtf(var + 1e-5f) * wln_g[c] + wln_b[c];
}

__global__ __launch_bounds__(256) void k_head_d(
        const float* __restrict__ vecbuf,
        const float* __restrict__ fuse_w1, const float* __restrict__ fuse_b1,
        const float* __restrict__ fuse_w2,
        float* __restrict__ out_fused) {
    __shared__ float red[256];
    int c = blockIdx.x;
    int t = threadIdx.x;
    int b = t & 15, kk = t >> 4;
    const float* wr = fuse_w1 + (size_t)c * (2 * HID) + kk * 32;
    const float* xr = vecbuf + (size_t)b * (2 * HID) + kk * 32;
    float s = 0.f;
#pragma unroll
    for (int i = 0; i < 32; i += 4) {
        float4 w4 = *(const float4*)(wr + i);
        float4 x4 = *(const float4*)(xr + i);
        s += x4.x * w4.x + x4.y * w4.y + x4.z * w4.z + x4.w * w4.w;
    }
    float tot = kred(s, red, b, kk);
    if (kk == 0) {
        float h1 = gelu_exact(tot + fuse_b1[c]);
#pragma unroll
        for (int o = 0; o < NBINS; o++)
            atomicAdd(&out_fused[b * NBINS + o], h1 * fuse_w2[o * HID + c]);
    }
}

extern "C" void kernel_launch(void* const* d_in, const int* in_sizes, int n_in,
                              void* d_out, int out_size, void* d_ws, size_t ws_size,
                              hipStream_t stream) {
    const float* emb_mirna  = (const float*)d_in[0];
    const float* emb_mrna   = (const float*)d_in[1];
    const float* w_mir2mrna = (const float*)d_in[2];
    const float* w_mrna2mir = (const float*)d_in[3];
    const float* w_mrna2pat = (const float*)d_in[4];
    const float* w_mir2pat  = (const float*)d_in[5];
    const float* reg_w_mrna = (const float*)d_in[6];
    const float* reg_b_mrna = (const float*)d_in[7];
    const float* reg_w_mirna= (const float*)d_in[8];
    const float* reg_b_mirna= (const float*)d_in[9];
    const float* proj_w     = (const float*)d_in[10];
    const float* proj_b     = (const float*)d_in[11];
    const float* ln_g       = (const float*)d_in[12];
    const float* ln_b       = (const float*)d_in[13];
    const float* omics_w    = (const float*)d_in[14];
    const float* omics_b    = (const float*)d_in[15];
    const float* wsi_w      = (const float*)d_in[16];
    const float* wsi_b      = (const float*)d_in[17];
    const float* mlp_w      = (const float*)d_in[18];
    const float* mlp_b      = (const float*)d_in[19];
    const float* wln_g      = (const float*)d_in[20];
    const float* wln_b      = (const float*)d_in[21];
    const float* fuse_w1    = (const float*)d_in[22];
    const float* fuse_b1    = (const float*)d_in[23];
    const float* fuse_w2    = (const float*)d_in[24];
    const float* fuse_b2    = (const float*)d_in[25];
    const float* patches    = (const float*)d_in[26];
    const float* mask       = (const float*)d_in[27];
    const int* src_m2M = (const int*)d_in[28];
    const int* dst_m2M = (const int*)d_in[29];
    const int* src_M2m = (const int*)d_in[30];
    const int* dst_M2m = (const int*)d_in[31];
    const int* src_M2p = (const int*)d_in[32];
    const int* dst_M2p = (const int*)d_in[33];
    const int* src_m2p = (const int*)d_in[34];
    const int* dst_m2p = (const int*)d_in[35];

    float* ws = (float*)d_ws;
    // ---- zeroed region (tiny: no Wp, no cnt) ----
    size_t off = 0;
    float* acc_pat  = ws + off; off += (size_t)BB * HID;       // 4096
    float* pooled   = ws + off; off += (size_t)BB * PD;        // 16384
    float* masksum  = ws + off; off += BB;                     // 16
    size_t zero_floats = off;                                  // 20496 floats, %4==0
    // ---- non-zeroed region ----
    unsigned short* agg_bf = (unsigned short*)(ws + off); off += (size_t)NG * HID / 2;
    unsigned short* wb     = (unsigned short*)(ws + off); off += (size_t)2 * HID * HID / 2;
    unsigned short* embB_mir  = (unsigned short*)(ws + off); off += (size_t)NMIR * HID / 2;
    unsigned short* embB_mrna = (unsigned short*)(ws + off); off += (size_t)NMRNA * HID / 2;
    float* pg       = ws + off; off += (size_t)BB * HID;
    float* wt       = ws + off; off += (size_t)BB * HID;
    float* ml       = ws + off; off += (size_t)BB * HID;
    float* vecbuf   = ws + off; off += (size_t)BB * 2 * HID;
    int* histR      = (int*)(ws + off); off += (size_t)NBR * NG;
    int* histP      = (int*)(ws + off); off += (size_t)NBP * NG;
    int* baseR      = (int*)(ws + off); off += (size_t)NBR * NG;   // relative
    int* baseP      = (int*)(ws + off); off += (size_t)NBP * NG;   // relative
    int* cntR       = (int*)(ws + off); off += NG;
    int* cntP       = (int*)(ws + off); off += NG;
    int* rowptrR    = (int*)(ws + off); off += NG + 2;
    int* rowptrP    = (int*)(ws + off); off += NG + 2;
    int2* epR       = (int2*)(ws + off); off += (size_t)2 * (2 * EREG);
    int2* epP       = (int2*)(ws + off); off += (size_t)2 * (EPM + EPI);

    float* out_fused = (float*)d_out;               // [16,4]
    float* out_omics = (float*)d_out + BB * NBINS;  // [16,4]

    hipMemsetAsync(d_ws, 0, zero_floats * sizeof(float), stream);

    // 1. conversions (streaming, no atomics)
    k_cvt<<<CVT_TOTAL, 256, 0, stream>>>(
        emb_mirna, emb_mrna, embB_mir, embB_mrna,
        reg_w_mrna, reg_w_mirna, wb);

    // 2-5. counting-sort CSR build — zero global atomics, parallel scan
    k_hist<<<NBR + NBP, 1024, 0, stream>>>(
        dst_m2M, dst_M2m, src_M2p, src_m2p, histR, histP);
    k_colsum<<<2 * CS_B, 256, 0, stream>>>(histR, histP, baseR, baseP, cntR, cntP);
    k_scan_small<<<2, 1024, 0, stream>>>(cntR, cntP, rowptrR, rowptrP);
    k_place<<<NBR + NBP, 1024, 0, stream>>>(
        src_m2M, dst_m2M, w_mir2mrna, src_M2m, dst_M2m, w_mrna2mir,
        src_M2p, dst_M2p, w_mrna2pat, src_m2p, dst_m2p, w_mir2pat,
        baseR, baseP, rowptrR, rowptrP, epR, epP);

    // 6. wsi masked pooling
    k_pool<<<dim3(PSLICES, BB), 256, 0, stream>>>(patches, mask, pooled, masksum);

    // 7. CSR gather from bf16 embeddings
    k_gather2<<<NG, 256, 0, stream>>>(embB_mir, embB_mrna, rowptrR, epR, agg_bf);

    // 8. MFMA node update + fused patient readout (pat weights from sorted epP)
    k_update2<<<NG / 16, 256, 0, stream>>>(agg_bf, emb_mrna, emb_mirna, wb,
                                           reg_b_mrna, reg_b_mirna,
                                           rowptrP, epP, acc_pat);

    // 9-12. head chain, column-parallel
    k_head_a<<<HID, 256, 0, stream>>>(acc_pat, pooled, masksum,
                                      proj_w, proj_b, wsi_w, wsi_b, pg, wt);
    k_head_b<<<HID, 256, 0, stream>>>(wt, mlp_w, mlp_b, ml);
    k_head_c<<<BB, 256, 0, stream>>>(pg, ml, ln_g, ln_b, wln_g, wln_b,
                                     omics_w, omics_b, fuse_b2,
                                     vecbuf, out_omics, out_fused);
    k_head_d<<<HID, 256, 0, stream>>>(vecbuf, fuse_w1, fuse_b1, fuse_w2, out_fused);
}

// Round 8
// 533.325 us; speedup vs baseline: 1.8668x; 1.1203x over previous
//
#include <hip/hip_runtime.h>
#include <math.h>

#define HID 256
#define NBINS 4
#define NMIR 2000
#define NMRNA 20000
#define NG (NMRNA + NMIR)   // 22000 union gene space
#define BB 16
#define NP 2048
#define PD 1024
#define EREG 300000
#define EPM 320000
#define EPI 32000

typedef __attribute__((ext_vector_type(8))) short bf16x8;
typedef __attribute__((ext_vector_type(4))) float f32x4;

__device__ __forceinline__ float gelu_exact(float x) {
    return 0.5f * x * (1.0f + erff(x * 0.7071067811865475f));
}

// fp32 -> bf16 round-to-nearest-even (bits)
__device__ __forceinline__ unsigned short f2b(float f) {
    union { float f; unsigned int u; } v; v.f = f;
    unsigned int u = v.u + 0x7fffu + ((v.u >> 16) & 1u);
    return (unsigned short)(u >> 16);
}

__device__ __forceinline__ float b2f(unsigned short u) {
    union { unsigned int i; float f; } v; v.i = ((unsigned int)u) << 16;
    return v.f;
}

// blockDim.x == 256 assumed
__device__ __forceinline__ float block_reduce_sum(float v, float* red) {
    int c = threadIdx.x;
    red[c] = v;
    __syncthreads();
    for (int st = 128; st > 0; st >>= 1) {
        if (c < st) red[c] += red[c + st];
        __syncthreads();
    }
    float r = red[0];
    __syncthreads();
    return r;
}

// 256-thread block laid out as (b = t&15, kk = t>>4); reduce over kk, result to all
__device__ __forceinline__ float kred(float v, float* red, int b, int kk) {
    red[kk * 16 + b] = v;
    __syncthreads();
    for (int st = 8; st >= 1; st >>= 1) {
        if (kk < st) red[kk * 16 + b] += red[(kk + st) * 16 + b];
        __syncthreads();
    }
    float r = red[b];
    __syncthreads();
    return r;
}

// ================= conversions: emb->bf16 + reg weights->bf16 =================
#define CVT_EMB ((NG * HID) / 4096)              // 1375 blocks, 16 elems/thread
#define CVT_F2B ((2 * HID * HID) / 4096)         // 32
#define CVT_TOTAL (CVT_EMB + CVT_F2B)

__global__ __launch_bounds__(256) void k_cvt(
        const float* __restrict__ emb_mirna, const float* __restrict__ emb_mrna,
        unsigned short* __restrict__ embB_mir, unsigned short* __restrict__ embB_mrna,
        const float* __restrict__ regwA, const float* __restrict__ regwB,
        unsigned short* __restrict__ wb) {
    int bid = blockIdx.x;
    int t = threadIdx.x;
    if (bid < CVT_EMB) {
        const size_t NM = (size_t)NMIR * HID;  // 512000; 4096-block boundary aligned (125*4096)
        float4 v[4];
#pragma unroll
        for (int k = 0; k < 4; k++) {
            size_t e = (size_t)bid * 4096 + k * 1024 + t * 4;
            v[k] = (e < NM) ? *(const float4*)(emb_mirna + e)
                            : *(const float4*)(emb_mrna + (e - NM));
        }
#pragma unroll
        for (int k = 0; k < 4; k++) {
            size_t e = (size_t)bid * 4096 + k * 1024 + t * 4;
            ushort4 u = { f2b(v[k].x), f2b(v[k].y), f2b(v[k].z), f2b(v[k].w) };
            if (e < NM) *(ushort4*)(embB_mir + e) = u;
            else        *(ushort4*)(embB_mrna + (e - NM)) = u;
        }
        return;
    }
    bid -= CVT_EMB;
    {
        const size_t NW = (size_t)HID * HID;   // 65536; aligned at block 16
        float4 v[4];
#pragma unroll
        for (int k = 0; k < 4; k++) {
            size_t e = (size_t)bid * 4096 + k * 1024 + t * 4;
            v[k] = (e < NW) ? *(const float4*)(regwA + e)
                            : *(const float4*)(regwB + (e - NW));
        }
#pragma unroll
        for (int k = 0; k < 4; k++) {
            size_t e = (size_t)bid * 4096 + k * 1024 + t * 4;
            ushort4 u = { f2b(v[k].x), f2b(v[k].y), f2b(v[k].z), f2b(v[k].w) };
            *(ushort4*)(wb + e) = u;
        }
    }
}

// ================= counting-sort CSR build: ZERO global atomics =================
// 160 blocks total (was 24): the r7 profile showed k_place/k_hist at 3% occupancy
// (24 blocks, 1/CU due to 88KB LDS). More chunks = more CUs in flight.
#define NBR 128
#define NBP 32
#define PER_R ((2 * EREG + NBR - 1) / NBR)   // 4688
#define PER_P ((EPM + EPI + NBP - 1) / NBP)  // 11000

__global__ __launch_bounds__(1024) void k_hist(
        const int* __restrict__ dR1, const int* __restrict__ dR2,
        const int* __restrict__ sP1, const int* __restrict__ sP2,
        int* __restrict__ histR, int* __restrict__ histP) {
    __shared__ int lh[NG];
    int t = threadIdx.x, bid = blockIdx.x;
    for (int i = t; i < NG; i += 1024) lh[i] = 0;
    __syncthreads();
    if (bid < NBR) {
        int beg = bid * PER_R, end = min(beg + PER_R, 2 * EREG);
        for (int i = beg + t; i < end; i += 1024) {
            int d = (i < EREG) ? dR1[i] : NMRNA + dR2[i - EREG];
            atomicAdd(&lh[d], 1);      // LDS atomic
        }
        __syncthreads();
        int* out = histR + (size_t)bid * NG;
        for (int i = t; i < NG; i += 1024) out[i] = lh[i];
    } else {
        int pb = bid - NBR;
        int beg = pb * PER_P, end = min(beg + PER_P, EPM + EPI);
        for (int i = beg + t; i < end; i += 1024) {
            int g = (i < EPM) ? sP1[i] : NMRNA + sP2[i - EPM];
            atomicAdd(&lh[g], 1);      // LDS atomic
        }
        __syncthreads();
        int* out = histP + (size_t)pb * NG;
        for (int i = t; i < NG; i += 1024) out[i] = lh[i];
    }
}

// ---- per-gene running sum over chunks (coalesced): baseRel + cnt ----
#define CS_B ((NG + 255) / 256)   // 86 blocks per space
__global__ __launch_bounds__(256) void k_colsum(
        const int* __restrict__ histR, const int* __restrict__ histP,
        int* __restrict__ baseR, int* __restrict__ baseP,
        int* __restrict__ cntR, int* __restrict__ cntP) {
    int bid = blockIdx.x;
    if (bid < CS_B) {
        int i = bid * 256 + threadIdx.x;
        if (i >= NG) return;
        int run = 0;
        for (int b = 0; b < NBR; b++) {
            baseR[(size_t)b * NG + i] = run;      // relative base
            run += histR[(size_t)b * NG + i];
        }
        cntR[i] = run;
    } else {
        int i = (bid - CS_B) * 256 + threadIdx.x;
        if (i >= NG) return;
        int run = 0;
        for (int b = 0; b < NBP; b++) {
            baseP[(size_t)b * NG + i] = run;
            run += histP[(size_t)b * NG + i];
        }
        cntP[i] = run;
    }
}

// ---- scan over cnt only (the proven round-2..5 shape) ----
__global__ __launch_bounds__(1024) void k_scan_small(
        const int* __restrict__ cntR, const int* __restrict__ cntP,
        int* __restrict__ rowptrR, int* __restrict__ rowptrP) {
    __shared__ int part[1024];
    const int* cnt = blockIdx.x ? cntP : cntR;
    int* rowptr = blockIdx.x ? rowptrP : rowptrR;
    int t = threadIdx.x;
    const int chunk = (NG + 1023) >> 10;   // 22
    int beg = t * chunk, end = min(beg + chunk, NG);
    int s = 0;
    for (int i = beg; i < end; i++) s += cnt[i];
    part[t] = s;
    __syncthreads();
    for (int st = 1; st < 1024; st <<= 1) {
        int v = (t >= st) ? part[t - st] : 0;
        __syncthreads();
        part[t] += v;
        __syncthreads();
    }
    int off = part[t] - s;   // exclusive prefix
    for (int i = beg; i < end; i++) {
        rowptr[i] = off;
        off += cnt[i];
    }
    if (end == NG) rowptr[NG] = off;
}

// Same chunking as k_hist; LDS cursors = rowptr + baseRel; rank via LDS atomic; plain stores.
__global__ __launch_bounds__(1024) void k_place(
        const int* __restrict__ sR1, const int* __restrict__ dR1, const float* __restrict__ wR1,
        const int* __restrict__ sR2, const int* __restrict__ dR2, const float* __restrict__ wR2,
        const int* __restrict__ sP1, const int* __restrict__ dP1, const float* __restrict__ wP1,
        const int* __restrict__ sP2, const int* __restrict__ dP2, const float* __restrict__ wP2,
        const int* __restrict__ baseR, const int* __restrict__ baseP,
        const int* __restrict__ rowptrR, const int* __restrict__ rowptrP,
        int2* __restrict__ epR, int2* __restrict__ epP) {
    __shared__ int lcur[NG];
    int t = threadIdx.x, bid = blockIdx.x;
    if (bid < NBR) {
        const int* base = baseR + (size_t)bid * NG;
        for (int i = t; i < NG; i += 1024) lcur[i] = rowptrR[i] + base[i];
        __syncthreads();
        int beg = bid * PER_R, end = min(beg + PER_R, 2 * EREG);
        for (int i = beg + t; i < end; i += 1024) {
            int d, s; float w;
            if (i < EREG) { d = dR1[i]; s = sR1[i]; w = wR1[i]; }
            else { int k = i - EREG; d = NMRNA + dR2[k]; s = sR2[k]; w = wR2[k]; }
            int p = atomicAdd(&lcur[d], 1);    // LDS atomic -> rank
            int2 e; e.x = s; e.y = __float_as_int(w);
            epR[p] = e;                        // plain scattered 8B store
        }
    } else {
        int pb = bid - NBR;
        const int* base = baseP + (size_t)pb * NG;
        for (int i = t; i < NG; i += 1024) lcur[i] = rowptrP[i] + base[i];
        __syncthreads();
        int beg = pb * PER_P, end = min(beg + PER_P, EPM + EPI);
        for (int i = beg + t; i < end; i += 1024) {
            int g, b; float w;
            if (i < EPM) { g = sP1[i]; b = dP1[i]; w = wP1[i]; }
            else { int k = i - EPM; g = NMRNA + sP2[k]; b = dP2[k]; w = wP2[k]; }
            int p = atomicAdd(&lcur[g], 1);
            int2 e; e.x = (g << 4) | b; e.y = __float_as_int(w);
            epP[p] = e;
        }
    }
}

// ---------- masked patch pooling: 2048 blocks ----------
#define PSLICES 128
#define PCHUNK (NP / PSLICES)   // 16
__global__ __launch_bounds__(256) void k_pool(
        const float* __restrict__ patches, const float* __restrict__ mask,
        float* __restrict__ pooled, float* __restrict__ masksum) {
    int b = blockIdx.y;
    int p0 = blockIdx.x * PCHUNK;
    int t = threadIdx.x;  // 256 threads x float4 = 1024 = PD
    float4 acc = {0.f, 0.f, 0.f, 0.f};
    float msum = 0.f;
#pragma unroll
    for (int pp = 0; pp < PCHUNK; pp++) {
        int p = p0 + pp;
        float m = mask[b * NP + p];  // uniform -> s_load
        float4 v = ((const float4*)(patches + ((size_t)b * NP + p) * PD))[t];
        msum += m;
        acc.x += m * v.x; acc.y += m * v.y; acc.z += m * v.z; acc.w += m * v.w;
    }
    float* op = pooled + (size_t)b * PD + t * 4;
    atomicAdd(op + 0, acc.x);
    atomicAdd(op + 1, acc.y);
    atomicAdd(op + 2, acc.z);
    atomicAdd(op + 3, acc.w);
    if (t == 0) atomicAdd(&masksum[b], msum);
}

// ---------- CSR gather from bf16 emb, unified rowptr, unroll-4 ----------
__global__ __launch_bounds__(256) void k_gather2(
        const unsigned short* __restrict__ embB_mir, const unsigned short* __restrict__ embB_mrna,
        const int* __restrict__ rowptrR, const int2* __restrict__ epR,
        unsigned short* __restrict__ agg) {
    __shared__ float lacc[4][HID];
    int n = blockIdx.x;
    const unsigned short* emb = (n < NMRNA) ? embB_mir : embB_mrna;
    int wv = threadIdx.x >> 6, l = threadIdx.x & 63;
    int beg = rowptrR[n], end = rowptrR[n + 1];
    float a0 = 0.f, a1 = 0.f, a2 = 0.f, a3 = 0.f;
    float c0 = 0.f, c1 = 0.f, c2 = 0.f, c3 = 0.f;
    float d0 = 0.f, d1 = 0.f, d2 = 0.f, d3 = 0.f;
    float g0 = 0.f, g1 = 0.f, g2 = 0.f, g3 = 0.f;
    int j = beg + wv;
    for (; j + 12 < end; j += 16) {
        int2 e0 = epR[j];             // wave-uniform -> s_load_dwordx2
        int2 e1 = epR[j + 4];
        int2 e2 = epR[j + 8];
        int2 e3 = epR[j + 12];
        float w0 = __int_as_float(e0.y), w1 = __int_as_float(e1.y);
        float w2 = __int_as_float(e2.y), w3 = __int_as_float(e3.y);
        ushort4 v0 = *(const ushort4*)(emb + (size_t)e0.x * HID + l * 4);
        ushort4 v1 = *(const ushort4*)(emb + (size_t)e1.x * HID + l * 4);
        ushort4 v2 = *(const ushort4*)(emb + (size_t)e2.x * HID + l * 4);
        ushort4 v3 = *(const ushort4*)(emb + (size_t)e3.x * HID + l * 4);
        a0 += w0 * b2f(v0.x); a1 += w0 * b2f(v0.y); a2 += w0 * b2f(v0.z); a3 += w0 * b2f(v0.w);
        c0 += w1 * b2f(v1.x); c1 += w1 * b2f(v1.y); c2 += w1 * b2f(v1.z); c3 += w1 * b2f(v1.w);
        d0 += w2 * b2f(v2.x); d1 += w2 * b2f(v2.y); d2 += w2 * b2f(v2.z); d3 += w2 * b2f(v2.w);
        g0 += w3 * b2f(v3.x); g1 += w3 * b2f(v3.y); g2 += w3 * b2f(v3.z); g3 += w3 * b2f(v3.w);
    }
    for (; j < end; j += 4) {
        int2 e0 = epR[j];
        float w0 = __int_as_float(e0.y);
        ushort4 v0 = *(const ushort4*)(emb + (size_t)e0.x * HID + l * 4);
        a0 += w0 * b2f(v0.x); a1 += w0 * b2f(v0.y); a2 += w0 * b2f(v0.z); a3 += w0 * b2f(v0.w);
    }
    float4 st = { a0 + c0 + d0 + g0, a1 + c1 + d1 + g1,
                  a2 + c2 + d2 + g2, a3 + c3 + d3 + g3 };
    ((float4*)lacc[wv])[l] = st;
    __syncthreads();
    int c = threadIdx.x;
    agg[(size_t)n * HID + c] = f2b(lacc[0][c] + lacc[1][c] + lacc[2][c] + lacc[3][c]);
}

// ---------- MFMA node update + fused patient readout (pat weights from sorted CSR) ----------
__global__ __launch_bounds__(256) void k_update2(
        const unsigned short* __restrict__ A,
        const float* __restrict__ emb_mrna, const float* __restrict__ emb_mirna,
        const unsigned short* __restrict__ wb,
        const float* __restrict__ bias_mrna, const float* __restrict__ bias_mirna,
        const int* __restrict__ rowptrP, const int2* __restrict__ epP,
        float* __restrict__ acc_pat) {
    __shared__ float ht[16][HID + 1];
    __shared__ float wtile[16][BB];
    int row0 = blockIdx.x * 16;   // global row (NG space); NMRNA % 16 == 0, never straddles
    const float* emb; const unsigned short* Wb; const float* bias; int base;
    if (row0 < NMRNA) { emb = emb_mrna;  Wb = wb;             bias = bias_mrna;  base = 0; }
    else              { emb = emb_mirna; Wb = wb + HID * HID; bias = bias_mirna; base = NMRNA; }
    int tid = threadIdx.x;
    if (tid < 16 * BB) wtile[tid >> 4][tid & 15] = 0.f;
    __syncthreads();
    // build 16x16 pat weight tile from sorted pat-edge segments (LDS atomics, ~256 edges)
    int pbeg = rowptrP[row0], pend = rowptrP[row0 + 16];
    for (int j = pbeg + tid; j < pend; j += 256) {
        int2 e = epP[j];
        atomicAdd(&wtile[(e.x >> 4) - row0][e.x & 15], __int_as_float(e.y));
    }
    int wv = tid >> 6;
    int lane = tid & 63;
    int m = lane & 15;   // A row offset / D col offset
    int q = lane >> 4;   // quad: k = q*8 + j
    bf16x8 afrag[8];
    const unsigned short* arow = A + (size_t)(row0 + m) * HID + q * 8;
#pragma unroll
    for (int kk = 0; kk < 8; kk++)
        afrag[kk] = *(const bf16x8*)(arow + kk * 32);
    f32x4 acc[4];
#pragma unroll
    for (int t = 0; t < 4; t++) acc[t] = (f32x4){0.f, 0.f, 0.f, 0.f};
    int col_base = wv * 64;
#pragma unroll
    for (int t = 0; t < 4; t++) {
        const unsigned short* brow = Wb + (size_t)(col_base + t * 16 + m) * HID + q * 8;
#pragma unroll
        for (int kk = 0; kk < 8; kk++) {
            bf16x8 bfrag = *(const bf16x8*)(brow + kk * 32);
            acc[t] = __builtin_amdgcn_mfma_f32_16x16x32_bf16(afrag[kk], bfrag, acc[t], 0, 0, 0);
        }
    }
#pragma unroll
    for (int t = 0; t < 4; t++) {
        int col = col_base + t * 16 + m;
        float bv = bias[col];
#pragma unroll
        for (int r = 0; r < 4; r++) {
            int lrow = q * 4 + r;                                // local row 0..15
            size_t idxe = (size_t)(row0 - base + lrow) * HID + col;
            ht[lrow][col] = emb[idxe] + gelu_exact(acc[t][r] + bv);
        }
    }
    __syncthreads();
    // fused skinny matmul: per col c, 16 patients x 16 rows
    int c = tid;
    float hv[16];
#pragma unroll
    for (int r = 0; r < 16; r++) hv[r] = ht[r][c];
#pragma unroll
    for (int b = 0; b < BB; b++) {
        float s = 0.f;
#pragma unroll
        for (int r = 0; r < 16; r++) s += wtile[r][b] * hv[r];   // LDS broadcast
        atomicAdd(&acc_pat[b * HID + c], s);                     // coalesced atomics
    }
}

// ================= head chain, column-parallel =================
__global__ __launch_bounds__(256) void k_head_a(
        const float* __restrict__ acc_pat, const float* __restrict__ pooled,
        const float* __restrict__ masksum,
        const float* __restrict__ proj_w, const float* __restrict__ proj_b,
        const float* __restrict__ wsi_w, const float* __restrict__ wsi_b,
        float* __restrict__ pg, float* __restrict__ wt) {
    __shared__ float red[256];
    int c = blockIdx.x;
    int t = threadIdx.x;
    int b = t & 15, kk = t >> 4;

    const float* wr = proj_w + (size_t)c * HID + kk * 16;
    const float* xr = acc_pat + (size_t)b * HID + kk * 16;
    float s = 0.f;
#pragma unroll
    for (int i = 0; i < 16; i += 4) {
        float4 w4 = *(const float4*)(wr + i);
        float4 x4 = *(const float4*)(xr + i);
        s += x4.x * w4.x + x4.y * w4.y + x4.z * w4.z + x4.w * w4.w;
    }
    float tot = kred(s, red, b, kk);
    if (kk == 0) pg[(size_t)b * HID + c] = gelu_exact(tot + proj_b[c]);

    const float* wr2 = wsi_w + (size_t)c * PD + kk * 64;
    const float* xr2 = pooled + (size_t)b * PD + kk * 64;
    float s2 = 0.f;
#pragma unroll
    for (int i = 0; i < 64; i += 4) {
        float4 w4 = *(const float4*)(wr2 + i);
        float4 x4 = *(const float4*)(xr2 + i);
        s2 += x4.x * w4.x + x4.y * w4.y + x4.z * w4.z + x4.w * w4.w;
    }
    float tot2 = kred(s2, red, b, kk);
    if (kk == 0) {
        float sm = masksum[b];
        float denom = fmaxf(sm, 1.0f);
        wt[(size_t)b * HID + c] = gelu_exact(tot2 / denom + wsi_b[c] * (sm / denom));
    }
}

__global__ __launch_bounds__(256) void k_head_b(
        const float* __restrict__ wt,
        const float* __restrict__ mlp_w, const float* __restrict__ mlp_b,
        float* __restrict__ ml) {
    __shared__ float red[256];
    int c = blockIdx.x;
    int t = threadIdx.x;
    int b = t & 15, kk = t >> 4;
    const float* wr = mlp_w + (size_t)c * HID + kk * 16;
    const float* xr = wt + (size_t)b * HID + kk * 16;
    float s = 0.f;
#pragma unroll
    for (int i = 0; i < 16; i += 4) {
        float4 w4 = *(const float4*)(wr + i);
        float4 x4 = *(const float4*)(xr + i);
        s += x4.x * w4.x + x4.y * w4.y + x4.z * w4.z + x4.w * w4.w;
    }
    float tot = kred(s, red, b, kk);
    if (kk == 0) ml[(size_t)b * HID + c] = gelu_exact(tot + mlp_b[c]);
}

__global__ __launch_bounds__(256) void k_head_c(
        const float* __restrict__ pg, const float* __restrict__ ml,
        const float* __restrict__ ln_g, const float* __restrict__ ln_b,
        const float* __restrict__ wln_g, const float* __restrict__ wln_b,
        const float* __restrict__ omics_w, const float* __restrict__ omics_b,
        const float* __restrict__ fuse_b2,
        float* __restrict__ vecbuf, float* __restrict__ out_omics,
        float* __restrict__ out_fused) {
    __shared__ float red[256];
    int b = blockIdx.x, c = threadIdx.x;
    if (c < NBINS) out_fused[b * NBINS + c] = fuse_b2[c];
    float g = pg[(size_t)b * HID + c];
    float mean = block_reduce_sum(g, red) * (1.0f / HID);
    float d = g - mean;
    float var = block_reduce_sum(d * d, red) * (1.0f / HID);
    float patv = d * rsqrtf(var + 1e-5f) * ln_g[c] + ln_b[c];
    vecbuf[(size_t)b * (2 * HID) + c] = patv;
    for (int o = 0; o < NBINS; o++) {
        float r = block_reduce_sum(patv * omics_w[o * HID + c], red);
        if (c == 0) out_omics[b * NBINS + o] = r + omics_b[o];
    }
    float m = ml[(size_t)b * HID + c];
    mean = block_reduce_sum(m, red) * (1.0f / HID);
    d = m - mean;
    var = block_reduce_sum(d * d, red) * (1.0f / HID);
    vecbuf[(size_t)b * (2 * HID) + HID + c] = d * rsqrtf(var + 1e-5f) * wln_g[c] + wln_b[c];
}

__global__ __launch_bounds__(256) void k_head_d(
        const float* __restrict__ vecbuf,
        const float* __restrict__ fuse_w1, const float* __restrict__ fuse_b1,
        const float* __restrict__ fuse_w2,
        float* __restrict__ out_fused) {
    __shared__ float red[256];
    int c = blockIdx.x;
    int t = threadIdx.x;
    int b = t & 15, kk = t >> 4;
    const float* wr = fuse_w1 + (size_t)c * (2 * HID) + kk * 32;
    const float* xr = vecbuf + (size_t)b * (2 * HID) + kk * 32;
    float s = 0.f;
#pragma unroll
    for (int i = 0; i < 32; i += 4) {
        float4 w4 = *(const float4*)(wr + i);
        float4 x4 = *(const float4*)(xr + i);
        s += x4.x * w4.x + x4.y * w4.y + x4.z * w4.z + x4.w * w4.w;
    }
    float tot = kred(s, red, b, kk);
    if (kk == 0) {
        float h1 = gelu_exact(tot + fuse_b1[c]);
#pragma unroll
        for (int o = 0; o < NBINS; o++)
            atomicAdd(&out_fused[b * NBINS + o], h1 * fuse_w2[o * HID + c]);
    }
}

extern "C" void kernel_launch(void* const* d_in, const int* in_sizes, int n_in,
                              void* d_out, int out_size, void* d_ws, size_t ws_size,
                              hipStream_t stream) {
    const float* emb_mirna  = (const float*)d_in[0];
    const float* emb_mrna   = (const float*)d_in[1];
    const float* w_mir2mrna = (const float*)d_in[2];
    const float* w_mrna2mir = (const float*)d_in[3];
    const float* w_mrna2pat = (const float*)d_in[4];
    const float* w_mir2pat  = (const float*)d_in[5];
    const float* reg_w_mrna = (const float*)d_in[6];
    const float* reg_b_mrna = (const float*)d_in[7];
    const float* reg_w_mirna= (const float*)d_in[8];
    const float* reg_b_mirna= (const float*)d_in[9];
    const float* proj_w     = (const float*)d_in[10];
    const float* proj_b     = (const float*)d_in[11];
    const float* ln_g       = (const float*)d_in[12];
    const float* ln_b       = (const float*)d_in[13];
    const float* omics_w    = (const float*)d_in[14];
    const float* omics_b    = (const float*)d_in[15];
    const float* wsi_w      = (const float*)d_in[16];
    const float* wsi_b      = (const float*)d_in[17];
    const float* mlp_w      = (const float*)d_in[18];
    const float* mlp_b      = (const float*)d_in[19];
    const float* wln_g      = (const float*)d_in[20];
    const float* wln_b      = (const float*)d_in[21];
    const float* fuse_w1    = (const float*)d_in[22];
    const float* fuse_b1    = (const float*)d_in[23];
    const float* fuse_w2    = (const float*)d_in[24];
    const float* fuse_b2    = (const float*)d_in[25];
    const float* patches    = (const float*)d_in[26];
    const float* mask       = (const float*)d_in[27];
    const int* src_m2M = (const int*)d_in[28];
    const int* dst_m2M = (const int*)d_in[29];
    const int* src_M2m = (const int*)d_in[30];
    const int* dst_M2m = (const int*)d_in[31];
    const int* src_M2p = (const int*)d_in[32];
    const int* dst_M2p = (const int*)d_in[33];
    const int* src_m2p = (const int*)d_in[34];
    const int* dst_m2p = (const int*)d_in[35];

    float* ws = (float*)d_ws;
    // ---- zeroed region (tiny: no Wp, no cnt) ----
    size_t off = 0;
    float* acc_pat  = ws + off; off += (size_t)BB * HID;       // 4096
    float* pooled   = ws + off; off += (size_t)BB * PD;        // 16384
    float* masksum  = ws + off; off += BB;                     // 16
    size_t zero_floats = off;                                  // 20496 floats, %4==0
    // ---- non-zeroed region ----
    unsigned short* agg_bf = (unsigned short*)(ws + off); off += (size_t)NG * HID / 2;
    unsigned short* wb     = (unsigned short*)(ws + off); off += (size_t)2 * HID * HID / 2;
    unsigned short* embB_mir  = (unsigned short*)(ws + off); off += (size_t)NMIR * HID / 2;
    unsigned short* embB_mrna = (unsigned short*)(ws + off); off += (size_t)NMRNA * HID / 2;
    float* pg       = ws + off; off += (size_t)BB * HID;
    float* wt       = ws + off; off += (size_t)BB * HID;
    float* ml       = ws + off; off += (size_t)BB * HID;
    float* vecbuf   = ws + off; off += (size_t)BB * 2 * HID;
    int* histR      = (int*)(ws + off); off += (size_t)NBR * NG;
    int* histP      = (int*)(ws + off); off += (size_t)NBP * NG;
    int* baseR      = (int*)(ws + off); off += (size_t)NBR * NG;   // relative
    int* baseP      = (int*)(ws + off); off += (size_t)NBP * NG;   // relative
    int* cntR       = (int*)(ws + off); off += NG;
    int* cntP       = (int*)(ws + off); off += NG;
    int* rowptrR    = (int*)(ws + off); off += NG + 2;
    int* rowptrP    = (int*)(ws + off); off += NG + 2;
    int2* epR       = (int2*)(ws + off); off += (size_t)2 * (2 * EREG);
    int2* epP       = (int2*)(ws + off); off += (size_t)2 * (EPM + EPI);

    float* out_fused = (float*)d_out;               // [16,4]
    float* out_omics = (float*)d_out + BB * NBINS;  // [16,4]

    hipMemsetAsync(d_ws, 0, zero_floats * sizeof(float), stream);

    // 1. conversions (streaming, no atomics)
    k_cvt<<<CVT_TOTAL, 256, 0, stream>>>(
        emb_mirna, emb_mrna, embB_mir, embB_mrna,
        reg_w_mrna, reg_w_mirna, wb);

    // 2-5. counting-sort CSR build — zero global atomics, 160-block decomposition
    k_hist<<<NBR + NBP, 1024, 0, stream>>>(
        dst_m2M, dst_M2m, src_M2p, src_m2p, histR, histP);
    k_colsum<<<2 * CS_B, 256, 0, stream>>>(histR, histP, baseR, baseP, cntR, cntP);
    k_scan_small<<<2, 1024, 0, stream>>>(cntR, cntP, rowptrR, rowptrP);
    k_place<<<NBR + NBP, 1024, 0, stream>>>(
        src_m2M, dst_m2M, w_mir2mrna, src_M2m, dst_M2m, w_mrna2mir,
        src_M2p, dst_M2p, w_mrna2pat, src_m2p, dst_m2p, w_mir2pat,
        baseR, baseP, rowptrR, rowptrP, epR, epP);

    // 6. wsi masked pooling
    k_pool<<<dim3(PSLICES, BB), 256, 0, stream>>>(patches, mask, pooled, masksum);

    // 7. CSR gather from bf16 embeddings
    k_gather2<<<NG, 256, 0, stream>>>(embB_mir, embB_mrna, rowptrR, epR, agg_bf);

    // 8. MFMA node update + fused patient readout (pat weights from sorted epP)
    k_update2<<<NG / 16, 256, 0, stream>>>(agg_bf, emb_mrna, emb_mirna, wb,
                                           reg_b_mrna, reg_b_mirna,
                                           rowptrP, epP, acc_pat);

    // 9-12. head chain, column-parallel
    k_head_a<<<HID, 256, 0, stream>>>(acc_pat, pooled, masksum,
                                      proj_w, proj_b, wsi_w, wsi_b, pg, wt);
    k_head_b<<<HID, 256, 0, stream>>>(wt, mlp_w, mlp_b, ml);
    k_head_c<<<BB, 256, 0, stream>>>(pg, ml, ln_g, ln_b, wln_g, wln_b,
                                     omics_w, omics_b, fuse_b2,
                                     vecbuf, out_omics, out_fused);
    k_head_d<<<HID, 256, 0, stream>>>(vecbuf, fuse_w1, fuse_b1, fuse_w2, out_fused);
}

// Round 9
// 518.989 us; speedup vs baseline: 1.9184x; 1.0276x over previous
//
#include <hip/hip_runtime.h>
#include <math.h>

#define HID 256
#define NBINS 4
#define NMIR 2000
#define NMRNA 20000
#define NG (NMRNA + NMIR)   // 22000 union gene space
#define BB 16
#define NP 2048
#define PD 1024
#define EREG 300000
#define EPM 320000
#define EPI 32000

typedef __attribute__((ext_vector_type(8))) short bf16x8;
typedef __attribute__((ext_vector_type(4))) float f32x4;

__device__ __forceinline__ float gelu_exact(float x) {
    return 0.5f * x * (1.0f + erff(x * 0.7071067811865475f));
}

// fp32 -> bf16 round-to-nearest-even (bits)
__device__ __forceinline__ unsigned short f2b(float f) {
    union { float f; unsigned int u; } v; v.f = f;
    unsigned int u = v.u + 0x7fffu + ((v.u >> 16) & 1u);
    return (unsigned short)(u >> 16);
}

__device__ __forceinline__ float b2f(unsigned short u) {
    union { unsigned int i; float f; } v; v.i = ((unsigned int)u) << 16;
    return v.f;
}

// blockDim.x == 256 assumed
__device__ __forceinline__ float block_reduce_sum(float v, float* red) {
    int c = threadIdx.x;
    red[c] = v;
    __syncthreads();
    for (int st = 128; st > 0; st >>= 1) {
        if (c < st) red[c] += red[c + st];
        __syncthreads();
    }
    float r = red[0];
    __syncthreads();
    return r;
}

// 256-thread block laid out as (b = t&15, kk = t>>4); reduce over kk, result to all
__device__ __forceinline__ float kred(float v, float* red, int b, int kk) {
    red[kk * 16 + b] = v;
    __syncthreads();
    for (int st = 8; st >= 1; st >>= 1) {
        if (kk < st) red[kk * 16 + b] += red[(kk + st) * 16 + b];
        __syncthreads();
    }
    float r = red[b];
    __syncthreads();
    return r;
}

// ================= fused front: pool | emb->bf16 | f2b | hist =================
// All mutually independent -> one dispatch; sections co-schedule across CUs
// (pool streams HBM while hist hammers LDS atomics). Hist counters packed
// 2x16-bit per word: 44 KB LDS -> 2 blocks/CU (full 32-wave occupancy).
#define NBR 128
#define NBP 32
#define PER_R ((2 * EREG + NBR - 1) / NBR)   // 4688  (< 65536: 16-bit safe)
#define PER_P ((EPM + EPI + NBP - 1) / NBP)  // 11000 (< 65536: 16-bit safe)

#define FR_POOL 512                          // 32 slices x 16 patients
#define FR_EMB ((NG * HID) / 4096)           // 1375 (1024 thr x 1 float4)
#define FR_F2B ((2 * HID * HID) / 4096)      // 32
#define FR_TOTAL (FR_POOL + FR_EMB + FR_F2B + NBR + NBP)

__global__ __launch_bounds__(1024) void k_front(
        const float* __restrict__ patches, const float* __restrict__ mask,
        float* __restrict__ pooled, float* __restrict__ masksum,
        const float* __restrict__ emb_mirna, const float* __restrict__ emb_mrna,
        unsigned short* __restrict__ embB_mir, unsigned short* __restrict__ embB_mrna,
        const float* __restrict__ regwA, const float* __restrict__ regwB,
        unsigned short* __restrict__ wb,
        const int* __restrict__ dR1, const int* __restrict__ dR2,
        const int* __restrict__ sP1, const int* __restrict__ sP2,
        int* __restrict__ histR, int* __restrict__ histP) {
    __shared__ int lh[NG / 2];   // 44 KB, hist sections only
    int bid = blockIdx.x;
    int t = threadIdx.x;
    if (bid < FR_POOL) {
        // ---- masked patch pooling: 64 patches/block, 4 sub-groups of 256 ----
        int slice = bid & 31, b = bid >> 5;
        int sub = t >> 8, col = t & 255;
        int p0 = slice * 64 + sub * 16;
        float4 acc = {0.f, 0.f, 0.f, 0.f};
        float msum = 0.f;
#pragma unroll
        for (int pp = 0; pp < 16; pp++) {
            int p = p0 + pp;
            float m = mask[b * NP + p];  // uniform per sub -> s_load
            float4 v = ((const float4*)(patches + ((size_t)b * NP + p) * PD))[col];
            msum += m;
            acc.x += m * v.x; acc.y += m * v.y; acc.z += m * v.z; acc.w += m * v.w;
        }
        float* op = pooled + (size_t)b * PD + col * 4;
        atomicAdd(op + 0, acc.x);
        atomicAdd(op + 1, acc.y);
        atomicAdd(op + 2, acc.z);
        atomicAdd(op + 3, acc.w);
        if (col == 0) atomicAdd(&masksum[b], msum);
        return;
    }
    bid -= FR_POOL;
    if (bid < FR_EMB) {
        // ---- embeddings -> bf16: 1024 threads x 1 float4 ----
        const size_t NM = (size_t)NMIR * HID;  // 512000 = 125 * 4096, boundary-aligned
        size_t e = (size_t)bid * 4096 + t * 4;
        float4 v;
        unsigned short* o;
        if (e < NM) { v = *(const float4*)(emb_mirna + e); o = embB_mir + e; }
        else        { v = *(const float4*)(emb_mrna + (e - NM)); o = embB_mrna + (e - NM); }
        ushort4 u = { f2b(v.x), f2b(v.y), f2b(v.z), f2b(v.w) };
        *(ushort4*)o = u;
        return;
    }
    bid -= FR_EMB;
    if (bid < FR_F2B) {
        // ---- reg weights -> bf16 ----
        const size_t NW = (size_t)HID * HID;   // 65536 = 16 * 4096, boundary-aligned
        size_t e = (size_t)bid * 4096 + t * 4;
        float4 v;
        if (e < NW) v = *(const float4*)(regwA + e);
        else v = *(const float4*)(regwB + (e - NW));
        ushort4 u = { f2b(v.x), f2b(v.y), f2b(v.z), f2b(v.w) };
        *(ushort4*)(wb + e) = u;
        return;
    }
    bid -= FR_F2B;
    // ---- histograms, packed 16-bit LDS counters ----
    for (int i = t; i < NG / 2; i += 1024) lh[i] = 0;
    __syncthreads();
    if (bid < NBR) {
        int beg = bid * PER_R, end = min(beg + PER_R, 2 * EREG);
        for (int i = beg + t; i < end; i += 1024) {
            int d = (i < EREG) ? dR1[i] : NMRNA + dR2[i - EREG];
            atomicAdd(&lh[d >> 1], 1u << ((d & 1) << 4));   // LDS atomic, packed
        }
        __syncthreads();
        int* out = histR + (size_t)bid * NG;
        for (int i = t; i < NG; i += 1024)
            out[i] = (lh[i >> 1] >> ((i & 1) << 4)) & 0xFFFF;
    } else {
        int pb = bid - NBR;
        int beg = pb * PER_P, end = min(beg + PER_P, EPM + EPI);
        for (int i = beg + t; i < end; i += 1024) {
            int g = (i < EPM) ? sP1[i] : NMRNA + sP2[i - EPM];
            atomicAdd(&lh[g >> 1], 1u << ((g & 1) << 4));
        }
        __syncthreads();
        int* out = histP + (size_t)pb * NG;
        for (int i = t; i < NG; i += 1024)
            out[i] = (lh[i >> 1] >> ((i & 1) << 4)) & 0xFFFF;
    }
}

// ---- per-gene running sum over chunks (coalesced): baseRel + cnt ----
#define CS_B ((NG + 255) / 256)   // 86 blocks per space
__global__ __launch_bounds__(256) void k_colsum(
        const int* __restrict__ histR, const int* __restrict__ histP,
        int* __restrict__ baseR, int* __restrict__ baseP,
        int* __restrict__ cntR, int* __restrict__ cntP) {
    int bid = blockIdx.x;
    if (bid < CS_B) {
        int i = bid * 256 + threadIdx.x;
        if (i >= NG) return;
        int run = 0;
        for (int b = 0; b < NBR; b++) {
            baseR[(size_t)b * NG + i] = run;      // relative base
            run += histR[(size_t)b * NG + i];
        }
        cntR[i] = run;
    } else {
        int i = (bid - CS_B) * 256 + threadIdx.x;
        if (i >= NG) return;
        int run = 0;
        for (int b = 0; b < NBP; b++) {
            baseP[(size_t)b * NG + i] = run;
            run += histP[(size_t)b * NG + i];
        }
        cntP[i] = run;
    }
}

// ---- scan over cnt only (the proven round-2..5 shape) ----
__global__ __launch_bounds__(1024) void k_scan_small(
        const int* __restrict__ cntR, const int* __restrict__ cntP,
        int* __restrict__ rowptrR, int* __restrict__ rowptrP) {
    __shared__ int part[1024];
    const int* cnt = blockIdx.x ? cntP : cntR;
    int* rowptr = blockIdx.x ? rowptrP : rowptrR;
    int t = threadIdx.x;
    const int chunk = (NG + 1023) >> 10;   // 22
    int beg = t * chunk, end = min(beg + chunk, NG);
    int s = 0;
    for (int i = beg; i < end; i++) s += cnt[i];
    part[t] = s;
    __syncthreads();
    for (int st = 1; st < 1024; st <<= 1) {
        int v = (t >= st) ? part[t - st] : 0;
        __syncthreads();
        part[t] += v;
        __syncthreads();
    }
    int off = part[t] - s;   // exclusive prefix
    for (int i = beg; i < end; i++) {
        rowptr[i] = off;
        off += cnt[i];
    }
    if (end == NG) rowptr[NG] = off;
}

// Same chunking as hist; LDS cursors = rowptr + baseRel; rank via LDS atomic; plain stores.
__global__ __launch_bounds__(1024) void k_place(
        const int* __restrict__ sR1, const int* __restrict__ dR1, const float* __restrict__ wR1,
        const int* __restrict__ sR2, const int* __restrict__ dR2, const float* __restrict__ wR2,
        const int* __restrict__ sP1, const int* __restrict__ dP1, const float* __restrict__ wP1,
        const int* __restrict__ sP2, const int* __restrict__ dP2, const float* __restrict__ wP2,
        const int* __restrict__ baseR, const int* __restrict__ baseP,
        const int* __restrict__ rowptrR, const int* __restrict__ rowptrP,
        int2* __restrict__ epR, int2* __restrict__ epP) {
    __shared__ int lcur[NG];
    int t = threadIdx.x, bid = blockIdx.x;
    if (bid < NBR) {
        const int* base = baseR + (size_t)bid * NG;
        for (int i = t; i < NG; i += 1024) lcur[i] = rowptrR[i] + base[i];
        __syncthreads();
        int beg = bid * PER_R, end = min(beg + PER_R, 2 * EREG);
        for (int i = beg + t; i < end; i += 1024) {
            int d, s; float w;
            if (i < EREG) { d = dR1[i]; s = sR1[i]; w = wR1[i]; }
            else { int k = i - EREG; d = NMRNA + dR2[k]; s = sR2[k]; w = wR2[k]; }
            int p = atomicAdd(&lcur[d], 1);    // LDS atomic -> rank
            int2 e; e.x = s; e.y = __float_as_int(w);
            epR[p] = e;                        // plain scattered 8B store
        }
    } else {
        int pb = bid - NBR;
        const int* base = baseP + (size_t)pb * NG;
        for (int i = t; i < NG; i += 1024) lcur[i] = rowptrP[i] + base[i];
        __syncthreads();
        int beg = pb * PER_P, end = min(beg + PER_P, EPM + EPI);
        for (int i = beg + t; i < end; i += 1024) {
            int g, b; float w;
            if (i < EPM) { g = sP1[i]; b = dP1[i]; w = wP1[i]; }
            else { int k = i - EPM; g = NMRNA + sP2[k]; b = dP2[k]; w = wP2[k]; }
            int p = atomicAdd(&lcur[g], 1);
            int2 e; e.x = (g << 4) | b; e.y = __float_as_int(w);
            epP[p] = e;
        }
    }
}

// ---------- CSR gather from bf16 emb, unified rowptr, unroll-4 ----------
__global__ __launch_bounds__(256) void k_gather2(
        const unsigned short* __restrict__ embB_mir, const unsigned short* __restrict__ embB_mrna,
        const int* __restrict__ rowptrR, const int2* __restrict__ epR,
        unsigned short* __restrict__ agg) {
    __shared__ float lacc[4][HID];
    int n = blockIdx.x;
    const unsigned short* emb = (n < NMRNA) ? embB_mir : embB_mrna;
    int wv = threadIdx.x >> 6, l = threadIdx.x & 63;
    int beg = rowptrR[n], end = rowptrR[n + 1];
    float a0 = 0.f, a1 = 0.f, a2 = 0.f, a3 = 0.f;
    float c0 = 0.f, c1 = 0.f, c2 = 0.f, c3 = 0.f;
    float d0 = 0.f, d1 = 0.f, d2 = 0.f, d3 = 0.f;
    float g0 = 0.f, g1 = 0.f, g2 = 0.f, g3 = 0.f;
    int j = beg + wv;
    for (; j + 12 < end; j += 16) {
        int2 e0 = epR[j];             // wave-uniform -> s_load_dwordx2
        int2 e1 = epR[j + 4];
        int2 e2 = epR[j + 8];
        int2 e3 = epR[j + 12];
        float w0 = __int_as_float(e0.y), w1 = __int_as_float(e1.y);
        float w2 = __int_as_float(e2.y), w3 = __int_as_float(e3.y);
        ushort4 v0 = *(const ushort4*)(emb + (size_t)e0.x * HID + l * 4);
        ushort4 v1 = *(const ushort4*)(emb + (size_t)e1.x * HID + l * 4);
        ushort4 v2 = *(const ushort4*)(emb + (size_t)e2.x * HID + l * 4);
        ushort4 v3 = *(const ushort4*)(emb + (size_t)e3.x * HID + l * 4);
        a0 += w0 * b2f(v0.x); a1 += w0 * b2f(v0.y); a2 += w0 * b2f(v0.z); a3 += w0 * b2f(v0.w);
        c0 += w1 * b2f(v1.x); c1 += w1 * b2f(v1.y); c2 += w1 * b2f(v1.z); c3 += w1 * b2f(v1.w);
        d0 += w2 * b2f(v2.x); d1 += w2 * b2f(v2.y); d2 += w2 * b2f(v2.z); d3 += w2 * b2f(v2.w);
        g0 += w3 * b2f(v3.x); g1 += w3 * b2f(v3.y); g2 += w3 * b2f(v3.z); g3 += w3 * b2f(v3.w);
    }
    for (; j < end; j += 4) {
        int2 e0 = epR[j];
        float w0 = __int_as_float(e0.y);
        ushort4 v0 = *(const ushort4*)(emb + (size_t)e0.x * HID + l * 4);
        a0 += w0 * b2f(v0.x); a1 += w0 * b2f(v0.y); a2 += w0 * b2f(v0.z); a3 += w0 * b2f(v0.w);
    }
    float4 st = { a0 + c0 + d0 + g0, a1 + c1 + d1 + g1,
                  a2 + c2 + d2 + g2, a3 + c3 + d3 + g3 };
    ((float4*)lacc[wv])[l] = st;
    __syncthreads();
    int c = threadIdx.x;
    agg[(size_t)n * HID + c] = f2b(lacc[0][c] + lacc[1][c] + lacc[2][c] + lacc[3][c]);
}

// ---------- MFMA node update + fused patient readout (pat weights from sorted CSR) ----------
__global__ __launch_bounds__(256) void k_update2(
        const unsigned short* __restrict__ A,
        const float* __restrict__ emb_mrna, const float* __restrict__ emb_mirna,
        const unsigned short* __restrict__ wb,
        const float* __restrict__ bias_mrna, const float* __restrict__ bias_mirna,
        const int* __restrict__ rowptrP, const int2* __restrict__ epP,
        float* __restrict__ acc_pat) {
    __shared__ float ht[16][HID + 1];
    __shared__ float wtile[16][BB];
    int row0 = blockIdx.x * 16;   // global row (NG space); NMRNA % 16 == 0, never straddles
    const float* emb; const unsigned short* Wb; const float* bias; int base;
    if (row0 < NMRNA) { emb = emb_mrna;  Wb = wb;             bias = bias_mrna;  base = 0; }
    else              { emb = emb_mirna; Wb = wb + HID * HID; bias = bias_mirna; base = NMRNA; }
    int tid = threadIdx.x;
    if (tid < 16 * BB) wtile[tid >> 4][tid & 15] = 0.f;
    __syncthreads();
    // build 16x16 pat weight tile from sorted pat-edge segments (LDS atomics, ~256 edges)
    int pbeg = rowptrP[row0], pend = rowptrP[row0 + 16];
    for (int j = pbeg + tid; j < pend; j += 256) {
        int2 e = epP[j];
        atomicAdd(&wtile[(e.x >> 4) - row0][e.x & 15], __int_as_float(e.y));
    }
    int wv = tid >> 6;
    int lane = tid & 63;
    int m = lane & 15;   // A row offset / D col offset
    int q = lane >> 4;   // quad: k = q*8 + j
    bf16x8 afrag[8];
    const unsigned short* arow = A + (size_t)(row0 + m) * HID + q * 8;
#pragma unroll
    for (int kk = 0; kk < 8; kk++)
        afrag[kk] = *(const bf16x8*)(arow + kk * 32);
    f32x4 acc[4];
#pragma unroll
    for (int t = 0; t < 4; t++) acc[t] = (f32x4){0.f, 0.f, 0.f, 0.f};
    int col_base = wv * 64;
#pragma unroll
    for (int t = 0; t < 4; t++) {
        const unsigned short* brow = Wb + (size_t)(col_base + t * 16 + m) * HID + q * 8;
#pragma unroll
        for (int kk = 0; kk < 8; kk++) {
            bf16x8 bfrag = *(const bf16x8*)(brow + kk * 32);
            acc[t] = __builtin_amdgcn_mfma_f32_16x16x32_bf16(afrag[kk], bfrag, acc[t], 0, 0, 0);
        }
    }
#pragma unroll
    for (int t = 0; t < 4; t++) {
        int col = col_base + t * 16 + m;
        float bv = bias[col];
#pragma unroll
        for (int r = 0; r < 4; r++) {
            int lrow = q * 4 + r;                                // local row 0..15
            size_t idxe = (size_t)(row0 - base + lrow) * HID + col;
            ht[lrow][col] = emb[idxe] + gelu_exact(acc[t][r] + bv);
        }
    }
    __syncthreads();
    // fused skinny matmul: per col c, 16 patients x 16 rows
    int c = tid;
    float hv[16];
#pragma unroll
    for (int r = 0; r < 16; r++) hv[r] = ht[r][c];
#pragma unroll
    for (int b = 0; b < BB; b++) {
        float s = 0.f;
#pragma unroll
        for (int r = 0; r < 16; r++) s += wtile[r][b] * hv[r];   // LDS broadcast
        atomicAdd(&acc_pat[b * HID + c], s);                     // coalesced atomics
    }
}

// ================= head chain, column-parallel =================
__global__ __launch_bounds__(256) void k_head_a(
        const float* __restrict__ acc_pat, const float* __restrict__ pooled,
        const float* __restrict__ masksum,
        const float* __restrict__ proj_w, const float* __restrict__ proj_b,
        const float* __restrict__ wsi_w, const float* __restrict__ wsi_b,
        float* __restrict__ pg, float* __restrict__ wt) {
    __shared__ float red[256];
    int c = blockIdx.x;
    int t = threadIdx.x;
    int b = t & 15, kk = t >> 4;

    const float* wr = proj_w + (size_t)c * HID + kk * 16;
    const float* xr = acc_pat + (size_t)b * HID + kk * 16;
    float s = 0.f;
#pragma unroll
    for (int i = 0; i < 16; i += 4) {
        float4 w4 = *(const float4*)(wr + i);
        float4 x4 = *(const float4*)(xr + i);
        s += x4.x * w4.x + x4.y * w4.y + x4.z * w4.z + x4.w * w4.w;
    }
    float tot = kred(s, red, b, kk);
    if (kk == 0) pg[(size_t)b * HID + c] = gelu_exact(tot + proj_b[c]);

    const float* wr2 = wsi_w + (size_t)c * PD + kk * 64;
    const float* xr2 = pooled + (size_t)b * PD + kk * 64;
    float s2 = 0.f;
#pragma unroll
    for (int i = 0; i < 64; i += 4) {
        float4 w4 = *(const float4*)(wr2 + i);
        float4 x4 = *(const float4*)(xr2 + i);
        s2 += x4.x * w4.x + x4.y * w4.y + x4.z * w4.z + x4.w * w4.w;
    }
    float tot2 = kred(s2, red, b, kk);
    if (kk == 0) {
        float sm = masksum[b];
        float denom = fmaxf(sm, 1.0f);
        wt[(size_t)b * HID + c] = gelu_exact(tot2 / denom + wsi_b[c] * (sm / denom));
    }
}

__global__ __launch_bounds__(256) void k_head_b(
        const float* __restrict__ wt,
        const float* __restrict__ mlp_w, const float* __restrict__ mlp_b,
        float* __restrict__ ml) {
    __shared__ float red[256];
    int c = blockIdx.x;
    int t = threadIdx.x;
    int b = t & 15, kk = t >> 4;
    const float* wr = mlp_w + (size_t)c * HID + kk * 16;
    const float* xr = wt + (size_t)b * HID + kk * 16;
    float s = 0.f;
#pragma unroll
    for (int i = 0; i < 16; i += 4) {
        float4 w4 = *(const float4*)(wr + i);
        float4 x4 = *(const float4*)(xr + i);
        s += x4.x * w4.x + x4.y * w4.y + x4.z * w4.z + x4.w * w4.w;
    }
    float tot = kred(s, red, b, kk);
    if (kk == 0) ml[(size_t)b * HID + c] = gelu_exact(tot + mlp_b[c]);
}

__global__ __launch_bounds__(256) void k_head_c(
        const float* __restrict__ pg, const float* __restrict__ ml,
        const float* __restrict__ ln_g, const float* __restrict__ ln_b,
        const float* __restrict__ wln_g, const float* __restrict__ wln_b,
        const float* __restrict__ omics_w, const float* __restrict__ omics_b,
        const float* __restrict__ fuse_b2,
        float* __restrict__ vecbuf, float* __restrict__ out_omics,
        float* __restrict__ out_fused) {
    __shared__ float red[256];
    int b = blockIdx.x, c = threadIdx.x;
    if (c < NBINS) out_fused[b * NBINS + c] = fuse_b2[c];
    float g = pg[(size_t)b * HID + c];
    float mean = block_reduce_sum(g, red) * (1.0f / HID);
    float d = g - mean;
    float var = block_reduce_sum(d * d, red) * (1.0f / HID);
    float patv = d * rsqrtf(var + 1e-5f) * ln_g[c] + ln_b[c];
    vecbuf[(size_t)b * (2 * HID) + c] = patv;
    for (int o = 0; o < NBINS; o++) {
        float r = block_reduce_sum(patv * omics_w[o * HID + c], red);
        if (c == 0) out_omics[b * NBINS + o] = r + omics_b[o];
    }
    float m = ml[(size_t)b * HID + c];
    mean = block_reduce_sum(m, red) * (1.0f / HID);
    d = m - mean;
    var = block_reduce_sum(d * d, red) * (1.0f / HID);
    vecbuf[(size_t)b * (2 * HID) + HID + c] = d * rsqrtf(var + 1e-5f) * wln_g[c] + wln_b[c];
}

__global__ __launch_bounds__(256) void k_head_d(
        const float* __restrict__ vecbuf,
        const float* __restrict__ fuse_w1, const float* __restrict__ fuse_b1,
        const float* __restrict__ fuse_w2,
        float* __restrict__ out_fused) {
    __shared__ float red[256];
    int c = blockIdx.x;
    int t = threadIdx.x;
    int b = t & 15, kk = t >> 4;
    const float* wr = fuse_w1 + (size_t)c * (2 * HID) + kk * 32;
    const float* xr = vecbuf + (size_t)b * (2 * HID) + kk * 32;
    float s = 0.f;
#pragma unroll
    for (int i = 0; i < 32; i += 4) {
        float4 w4 = *(const float4*)(wr + i);
        float4 x4 = *(const float4*)(xr + i);
        s += x4.x * w4.x + x4.y * w4.y + x4.z * w4.z + x4.w * w4.w;
    }
    float tot = kred(s, red, b, kk);
    if (kk == 0) {
        float h1 = gelu_exact(tot + fuse_b1[c]);
#pragma unroll
        for (int o = 0; o < NBINS; o++)
            atomicAdd(&out_fused[b * NBINS + o], h1 * fuse_w2[o * HID + c]);
    }
}

extern "C" void kernel_launch(void* const* d_in, const int* in_sizes, int n_in,
                              void* d_out, int out_size, void* d_ws, size_t ws_size,
                              hipStream_t stream) {
    const float* emb_mirna  = (const float*)d_in[0];
    const float* emb_mrna   = (const float*)d_in[1];
    const float* w_mir2mrna = (const float*)d_in[2];
    const float* w_mrna2mir = (const float*)d_in[3];
    const float* w_mrna2pat = (const float*)d_in[4];
    const float* w_mir2pat  = (const float*)d_in[5];
    const float* reg_w_mrna = (const float*)d_in[6];
    const float* reg_b_mrna = (const float*)d_in[7];
    const float* reg_w_mirna= (const float*)d_in[8];
    const float* reg_b_mirna= (const float*)d_in[9];
    const float* proj_w     = (const float*)d_in[10];
    const float* proj_b     = (const float*)d_in[11];
    const float* ln_g       = (const float*)d_in[12];
    const float* ln_b       = (const float*)d_in[13];
    const float* omics_w    = (const float*)d_in[14];
    const float* omics_b    = (const float*)d_in[15];
    const float* wsi_w      = (const float*)d_in[16];
    const float* wsi_b      = (const float*)d_in[17];
    const float* mlp_w      = (const float*)d_in[18];
    const float* mlp_b      = (const float*)d_in[19];
    const float* wln_g      = (const float*)d_in[20];
    const float* wln_b      = (const float*)d_in[21];
    const float* fuse_w1    = (const float*)d_in[22];
    const float* fuse_b1    = (const float*)d_in[23];
    const float* fuse_w2    = (const float*)d_in[24];
    const float* fuse_b2    = (const float*)d_in[25];
    const float* patches    = (const float*)d_in[26];
    const float* mask       = (const float*)d_in[27];
    const int* src_m2M = (const int*)d_in[28];
    const int* dst_m2M = (const int*)d_in[29];
    const int* src_M2m = (const int*)d_in[30];
    const int* dst_M2m = (const int*)d_in[31];
    const int* src_M2p = (const int*)d_in[32];
    const int* dst_M2p = (const int*)d_in[33];
    const int* src_m2p = (const int*)d_in[34];
    const int* dst_m2p = (const int*)d_in[35];

    float* ws = (float*)d_ws;
    // ---- zeroed region ----
    size_t off = 0;
    float* acc_pat  = ws + off; off += (size_t)BB * HID;       // 4096
    float* pooled   = ws + off; off += (size_t)BB * PD;        // 16384
    float* masksum  = ws + off; off += BB;                     // 16
    size_t zero_floats = off;                                  // 20496 floats, %4==0
    // ---- non-zeroed region ----
    unsigned short* agg_bf = (unsigned short*)(ws + off); off += (size_t)NG * HID / 2;
    unsigned short* wb     = (unsigned short*)(ws + off); off += (size_t)2 * HID * HID / 2;
    unsigned short* embB_mir  = (unsigned short*)(ws + off); off += (size_t)NMIR * HID / 2;
    unsigned short* embB_mrna = (unsigned short*)(ws + off); off += (size_t)NMRNA * HID / 2;
    float* pg       = ws + off; off += (size_t)BB * HID;
    float* wt       = ws + off; off += (size_t)BB * HID;
    float* ml       = ws + off; off += (size_t)BB * HID;
    float* vecbuf   = ws + off; off += (size_t)BB * 2 * HID;
    int* histR      = (int*)(ws + off); off += (size_t)NBR * NG;
    int* histP      = (int*)(ws + off); off += (size_t)NBP * NG;
    int* baseR      = (int*)(ws + off); off += (size_t)NBR * NG;   // relative
    int* baseP      = (int*)(ws + off); off += (size_t)NBP * NG;   // relative
    int* cntR       = (int*)(ws + off); off += NG;
    int* cntP       = (int*)(ws + off); off += NG;
    int* rowptrR    = (int*)(ws + off); off += NG + 2;
    int* rowptrP    = (int*)(ws + off); off += NG + 2;
    int2* epR       = (int2*)(ws + off); off += (size_t)2 * (2 * EREG);
    int2* epP       = (int2*)(ws + off); off += (size_t)2 * (EPM + EPI);

    float* out_fused = (float*)d_out;               // [16,4]
    float* out_omics = (float*)d_out + BB * NBINS;  // [16,4]

    hipMemsetAsync(d_ws, 0, zero_floats * sizeof(float), stream);

    // 1. fused front: pool + emb->bf16 + f2b + hist (independent sections, one dispatch)
    k_front<<<FR_TOTAL, 1024, 0, stream>>>(
        patches, mask, pooled, masksum,
        emb_mirna, emb_mrna, embB_mir, embB_mrna,
        reg_w_mrna, reg_w_mirna, wb,
        dst_m2M, dst_M2m, src_M2p, src_m2p, histR, histP);

    // 2-4. counting-sort CSR finish
    k_colsum<<<2 * CS_B, 256, 0, stream>>>(histR, histP, baseR, baseP, cntR, cntP);
    k_scan_small<<<2, 1024, 0, stream>>>(cntR, cntP, rowptrR, rowptrP);
    k_place<<<NBR + NBP, 1024, 0, stream>>>(
        src_m2M, dst_m2M, w_mir2mrna, src_M2m, dst_M2m, w_mrna2mir,
        src_M2p, dst_M2p, w_mrna2pat, src_m2p, dst_m2p, w_mir2pat,
        baseR, baseP, rowptrR, rowptrP, epR, epP);

    // 5. CSR gather from bf16 embeddings
    k_gather2<<<NG, 256, 0, stream>>>(embB_mir, embB_mrna, rowptrR, epR, agg_bf);

    // 6. MFMA node update + fused patient readout (pat weights from sorted epP)
    k_update2<<<NG / 16, 256, 0, stream>>>(agg_bf, emb_mrna, emb_mirna, wb,
                                           reg_b_mrna, reg_b_mirna,
                                           rowptrP, epP, acc_pat);

    // 7-10. head chain, column-parallel
    k_head_a<<<HID, 256, 0, stream>>>(acc_pat, pooled, masksum,
                                      proj_w, proj_b, wsi_w, wsi_b, pg, wt);
    k_head_b<<<HID, 256, 0, stream>>>(wt, mlp_w, mlp_b, ml);
    k_head_c<<<BB, 256, 0, stream>>>(pg, ml, ln_g, ln_b, wln_g, wln_b,
                                     omics_w, omics_b, fuse_b2,
                                     vecbuf, out_omics, out_fused);
    k_head_d<<<HID, 256, 0, stream>>>(vecbuf, fuse_w1, fuse_b1, fuse_w2, out_fused);
}

// Round 11
// 500.198 us; speedup vs baseline: 1.9905x; 1.0376x over previous
//
#include <hip/hip_runtime.h>
#include <math.h>

#define HID 256
#define NBINS 4
#define NMIR 2000
#define NMRNA 20000
#define NG (NMRNA + NMIR)   // 22000 union gene space
#define BB 16
#define NP 2048
#define PD 1024
#define EREG 300000
#define EPM 320000
#define EPI 32000
#define NSLOT 8             // acc_pat contention-split slots

typedef __attribute__((ext_vector_type(8))) short bf16x8;
typedef __attribute__((ext_vector_type(4))) float f32x4;

__device__ __forceinline__ float gelu_exact(float x) {
    return 0.5f * x * (1.0f + erff(x * 0.7071067811865475f));
}

// fp32 -> bf16 round-to-nearest-even (bits)
__device__ __forceinline__ unsigned short f2b(float f) {
    union { float f; unsigned int u; } v; v.f = f;
    unsigned int u = v.u + 0x7fffu + ((v.u >> 16) & 1u);
    return (unsigned short)(u >> 16);
}

__device__ __forceinline__ float b2f(unsigned short u) {
    union { unsigned int i; float f; } v; v.i = ((unsigned int)u) << 16;
    return v.f;
}

// blockDim.x == 256 assumed
__device__ __forceinline__ float block_reduce_sum(float v, float* red) {
    int c = threadIdx.x;
    red[c] = v;
    __syncthreads();
    for (int st = 128; st > 0; st >>= 1) {
        if (c < st) red[c] += red[c + st];
        __syncthreads();
    }
    float r = red[0];
    __syncthreads();
    return r;
}

// 256-thread block laid out as (b = t&15, kk = t>>4); reduce over kk, result to all
__device__ __forceinline__ float kred(float v, float* red, int b, int kk) {
    red[kk * 16 + b] = v;
    __syncthreads();
    for (int st = 8; st >= 1; st >>= 1) {
        if (kk < st) red[kk * 16 + b] += red[(kk + st) * 16 + b];
        __syncthreads();
    }
    float r = red[b];
    __syncthreads();
    return r;
}

// ================= fused front: pool | emb->bf16 | f2b | zero-acc | hist =================
// Pool: in-block LDS reduce -> plain stores to pooled_part (NO global atomics).
// Hist: packed 16-bit LDS counters (44 KB -> 2 blocks/CU).
#define NBR 128
#define NBP 32
#define PER_R ((2 * EREG + NBR - 1) / NBR)   // 4688  (< 65536: 16-bit safe)
#define PER_P ((EPM + EPI + NBP - 1) / NBP)  // 11000 (< 65536: 16-bit safe)

#define FR_POOL 512                          // 32 slices x 16 patients
#define FR_EMB ((NG * HID) / 4096)           // 1375 (1024 thr x 1 float4)
#define FR_F2B ((2 * HID * HID) / 4096)      // 32
#define FR_ZACC ((NSLOT * BB * HID) / 4096)  // 8
#define FR_TOTAL (FR_POOL + FR_EMB + FR_F2B + FR_ZACC + NBR + NBP)

__global__ __launch_bounds__(1024) void k_front(
        const float* __restrict__ patches, const float* __restrict__ mask,
        float* __restrict__ pooled_part, float* __restrict__ maskp,
        const float* __restrict__ emb_mirna, const float* __restrict__ emb_mrna,
        unsigned short* __restrict__ embB_mir, unsigned short* __restrict__ embB_mrna,
        const float* __restrict__ regwA, const float* __restrict__ regwB,
        unsigned short* __restrict__ wb,
        float* __restrict__ acc_slot,
        const int* __restrict__ dR1, const int* __restrict__ dR2,
        const int* __restrict__ sP1, const int* __restrict__ sP2,
        int* __restrict__ histR, int* __restrict__ histP) {
    __shared__ int lh[NG / 2];   // 44 KB; hist counters OR pool reduce scratch
    int bid = blockIdx.x;
    int t = threadIdx.x;
    if (bid < FR_POOL) {
        // ---- masked patch pooling: 64 patches/block, 4 sub-groups of 256 ----
        float* pl = (float*)lh;   // reuse: 4*1024 partials + 4 msum (16.4 KB < 44 KB)
        int slice = bid & 31, b = bid >> 5;
        int sub = t >> 8, col = t & 255;
        int p0 = slice * 64 + sub * 16;
        float4 acc = {0.f, 0.f, 0.f, 0.f};
        float msum = 0.f;
#pragma unroll
        for (int pp = 0; pp < 16; pp++) {
            int p = p0 + pp;
            float m = mask[b * NP + p];  // uniform per sub -> s_load
            float4 v = ((const float4*)(patches + ((size_t)b * NP + p) * PD))[col];
            msum += m;
            acc.x += m * v.x; acc.y += m * v.y; acc.z += m * v.z; acc.w += m * v.w;
        }
        ((float4*)pl)[sub * 256 + col] = acc;
        if (col == 0) pl[4096 + sub] = msum;
        __syncthreads();
        if (t < 256) {
            float4 a0 = ((float4*)pl)[t];
            float4 a1 = ((float4*)pl)[256 + t];
            float4 a2 = ((float4*)pl)[512 + t];
            float4 a3 = ((float4*)pl)[768 + t];
            float4 s4 = { a0.x + a1.x + a2.x + a3.x, a0.y + a1.y + a2.y + a3.y,
                          a0.z + a1.z + a2.z + a3.z, a0.w + a1.w + a2.w + a3.w };
            ((float4*)(pooled_part + ((size_t)slice * 16 + b) * PD))[t] = s4;
            if (t == 0)
                maskp[slice * 16 + b] = pl[4096] + pl[4097] + pl[4098] + pl[4099];
        }
        return;
    }
    bid -= FR_POOL;
    if (bid < FR_EMB) {
        // ---- embeddings -> bf16: 1024 threads x 1 float4 ----
        const size_t NM = (size_t)NMIR * HID;  // 512000 = 125 * 4096, boundary-aligned
        size_t e = (size_t)bid * 4096 + t * 4;
        float4 v;
        unsigned short* o;
        if (e < NM) { v = *(const float4*)(emb_mirna + e); o = embB_mir + e; }
        else        { v = *(const float4*)(emb_mrna + (e - NM)); o = embB_mrna + (e - NM); }
        ushort4 u = { f2b(v.x), f2b(v.y), f2b(v.z), f2b(v.w) };
        *(ushort4*)o = u;
        return;
    }
    bid -= FR_EMB;
    if (bid < FR_F2B) {
        // ---- reg weights -> bf16 ----
        const size_t NW = (size_t)HID * HID;   // 65536 = 16 * 4096, boundary-aligned
        size_t e = (size_t)bid * 4096 + t * 4;
        float4 v;
        if (e < NW) v = *(const float4*)(regwA + e);
        else v = *(const float4*)(regwB + (e - NW));
        ushort4 u = { f2b(v.x), f2b(v.y), f2b(v.z), f2b(v.w) };
        *(ushort4*)(wb + e) = u;
        return;
    }
    bid -= FR_F2B;
    if (bid < FR_ZACC) {
        // ---- zero acc_slot (replaces host memset; completes before k_update2) ----
        size_t e = (size_t)bid * 4096 + t * 4;
        float4 z = {0.f, 0.f, 0.f, 0.f};
        *(float4*)(acc_slot + e) = z;
        return;
    }
    bid -= FR_ZACC;
    // ---- histograms, packed 16-bit LDS counters ----
    for (int i = t; i < NG / 2; i += 1024) lh[i] = 0;
    __syncthreads();
    if (bid < NBR) {
        int beg = bid * PER_R, end = min(beg + PER_R, 2 * EREG);
        for (int i = beg + t; i < end; i += 1024) {
            int d = (i < EREG) ? dR1[i] : NMRNA + dR2[i - EREG];
            atomicAdd(&lh[d >> 1], 1u << ((d & 1) << 4));   // LDS atomic, packed
        }
        __syncthreads();
        int* out = histR + (size_t)bid * NG;
        for (int i = t; i < NG; i += 1024)
            out[i] = (lh[i >> 1] >> ((i & 1) << 4)) & 0xFFFF;
    } else {
        int pb = bid - NBR;
        int beg = pb * PER_P, end = min(beg + PER_P, EPM + EPI);
        for (int i = beg + t; i < end; i += 1024) {
            int g = (i < EPM) ? sP1[i] : NMRNA + sP2[i - EPM];
            atomicAdd(&lh[g >> 1], 1u << ((g & 1) << 4));
        }
        __syncthreads();
        int* out = histP + (size_t)pb * NG;
        for (int i = t; i < NG; i += 1024)
            out[i] = (lh[i >> 1] >> ((i & 1) << 4)) & 0xFFFF;
    }
}

// ---- colsum (base/cnt) + pooled/masksum reduce sections ----
#define CS_B ((NG + 255) / 256)    // 86 blocks per space
#define PR_B ((BB * PD) / 256)     // 64 pooled-reduce blocks
__global__ __launch_bounds__(256) void k_colsum(
        const int* __restrict__ histR, const int* __restrict__ histP,
        int* __restrict__ baseR, int* __restrict__ baseP,
        int* __restrict__ cntR, int* __restrict__ cntP,
        const float* __restrict__ pooled_part, const float* __restrict__ maskp,
        float* __restrict__ pooled, float* __restrict__ masksum) {
    int bid = blockIdx.x;
    if (bid < CS_B) {
        int i = bid * 256 + threadIdx.x;
        if (i >= NG) return;
        int run = 0;
        for (int b = 0; b < NBR; b++) {
            baseR[(size_t)b * NG + i] = run;      // relative base
            run += histR[(size_t)b * NG + i];
        }
        cntR[i] = run;
        return;
    }
    if (bid < 2 * CS_B) {
        int i = (bid - CS_B) * 256 + threadIdx.x;
        if (i >= NG) return;
        int run = 0;
        for (int b = 0; b < NBP; b++) {
            baseP[(size_t)b * NG + i] = run;
            run += histP[(size_t)b * NG + i];
        }
        cntP[i] = run;
        return;
    }
    // pooled reduce: sum 32 slice-partials per output elem
    int pr = bid - 2 * CS_B;
    int o = pr * 256 + threadIdx.x;     // 0 .. BB*PD-1
    float s = 0.f;
    for (int sl = 0; sl < 32; sl++) s += pooled_part[(size_t)sl * BB * PD + o];
    pooled[o] = s;
    if (pr == 0 && threadIdx.x < BB) {
        float ms = 0.f;
        for (int sl = 0; sl < 32; sl++) ms += maskp[sl * BB + threadIdx.x];
        masksum[threadIdx.x] = ms;
    }
}

// ---- scan over cnt only (the proven round-2..5 shape) ----
__global__ __launch_bounds__(1024) void k_scan_small(
        const int* __restrict__ cntR, const int* __restrict__ cntP,
        int* __restrict__ rowptrR, int* __restrict__ rowptrP) {
    __shared__ int part[1024];
    const int* cnt = blockIdx.x ? cntP : cntR;
    int* rowptr = blockIdx.x ? rowptrP : rowptrR;
    int t = threadIdx.x;
    const int chunk = (NG + 1023) >> 10;   // 22
    int beg = t * chunk, end = min(beg + chunk, NG);
    int s = 0;
    for (int i = beg; i < end; i++) s += cnt[i];
    part[t] = s;
    __syncthreads();
    for (int st = 1; st < 1024; st <<= 1) {
        int v = (t >= st) ? part[t - st] : 0;
        __syncthreads();
        part[t] += v;
        __syncthreads();
    }
    int off = part[t] - s;   // exclusive prefix
    for (int i = beg; i < end; i++) {
        rowptr[i] = off;
        off += cnt[i];
    }
    if (end == NG) rowptr[NG] = off;
}

// Same chunking as hist; LDS cursors = rowptr + baseRel; rank via LDS atomic; plain stores.
__global__ __launch_bounds__(1024) void k_place(
        const int* __restrict__ sR1, const int* __restrict__ dR1, const float* __restrict__ wR1,
        const int* __restrict__ sR2, const int* __restrict__ dR2, const float* __restrict__ wR2,
        const int* __restrict__ sP1, const int* __restrict__ dP1, const float* __restrict__ wP1,
        const int* __restrict__ sP2, const int* __restrict__ dP2, const float* __restrict__ wP2,
        const int* __restrict__ baseR, const int* __restrict__ baseP,
        const int* __restrict__ rowptrR, const int* __restrict__ rowptrP,
        int2* __restrict__ epR, int2* __restrict__ epP) {
    __shared__ int lcur[NG];
    int t = threadIdx.x, bid = blockIdx.x;
    if (bid < NBR) {
        const int* base = baseR + (size_t)bid * NG;
        for (int i = t; i < NG; i += 1024) lcur[i] = rowptrR[i] + base[i];
        __syncthreads();
        int beg = bid * PER_R, end = min(beg + PER_R, 2 * EREG);
        for (int i = beg + t; i < end; i += 1024) {
            int d, s; float w;
            if (i < EREG) { d = dR1[i]; s = sR1[i]; w = wR1[i]; }
            else { int k = i - EREG; d = NMRNA + dR2[k]; s = sR2[k]; w = wR2[k]; }
            int p = atomicAdd(&lcur[d], 1);    // LDS atomic -> rank
            int2 e; e.x = s; e.y = __float_as_int(w);
            epR[p] = e;                        // plain scattered 8B store
        }
    } else {
        int pb = bid - NBR;
        const int* base = baseP + (size_t)pb * NG;
        for (int i = t; i < NG; i += 1024) lcur[i] = rowptrP[i] + base[i];
        __syncthreads();
        int beg = pb * PER_P, end = min(beg + PER_P, EPM + EPI);
        for (int i = beg + t; i < end; i += 1024) {
            int g, b; float w;
            if (i < EPM) { g = sP1[i]; b = dP1[i]; w = wP1[i]; }
            else { int k = i - EPM; g = NMRNA + sP2[k]; b = dP2[k]; w = wP2[k]; }
            int p = atomicAdd(&lcur[g], 1);
            int2 e; e.x = (g << 4) | b; e.y = __float_as_int(w);
            epP[p] = e;
        }
    }
}

// ---------- CSR gather from bf16 emb, unified rowptr, unroll-4 ----------
__global__ __launch_bounds__(256) void k_gather2(
        const unsigned short* __restrict__ embB_mir, const unsigned short* __restrict__ embB_mrna,
        const int* __restrict__ rowptrR, const int2* __restrict__ epR,
        unsigned short* __restrict__ agg) {
    __shared__ float lacc[4][HID];
    int n = blockIdx.x;
    const unsigned short* emb = (n < NMRNA) ? embB_mir : embB_mrna;
    int wv = threadIdx.x >> 6, l = threadIdx.x & 63;
    int beg = rowptrR[n], end = rowptrR[n + 1];
    float a0 = 0.f, a1 = 0.f, a2 = 0.f, a3 = 0.f;
    float c0 = 0.f, c1 = 0.f, c2 = 0.f, c3 = 0.f;
    float d0 = 0.f, d1 = 0.f, d2 = 0.f, d3 = 0.f;
    float g0 = 0.f, g1 = 0.f, g2 = 0.f, g3 = 0.f;
    int j = beg + wv;
    for (; j + 12 < end; j += 16) {
        int2 e0 = epR[j];             // wave-uniform -> s_load_dwordx2
        int2 e1 = epR[j + 4];
        int2 e2 = epR[j + 8];
        int2 e3 = epR[j + 12];
        float w0 = __int_as_float(e0.y), w1 = __int_as_float(e1.y);
        float w2 = __int_as_float(e2.y), w3 = __int_as_float(e3.y);
        ushort4 v0 = *(const ushort4*)(emb + (size_t)e0.x * HID + l * 4);
        ushort4 v1 = *(const ushort4*)(emb + (size_t)e1.x * HID + l * 4);
        ushort4 v2 = *(const ushort4*)(emb + (size_t)e2.x * HID + l * 4);
        ushort4 v3 = *(const ushort4*)(emb + (size_t)e3.x * HID + l * 4);
        a0 += w0 * b2f(v0.x); a1 += w0 * b2f(v0.y); a2 += w0 * b2f(v0.z); a3 += w0 * b2f(v0.w);
        c0 += w1 * b2f(v1.x); c1 += w1 * b2f(v1.y); c2 += w1 * b2f(v1.z); c3 += w1 * b2f(v1.w);
        d0 += w2 * b2f(v2.x); d1 += w2 * b2f(v2.y); d2 += w2 * b2f(v2.z); d3 += w2 * b2f(v2.w);
        g0 += w3 * b2f(v3.x); g1 += w3 * b2f(v3.y); g2 += w3 * b2f(v3.z); g3 += w3 * b2f(v3.w);
    }
    for (; j < end; j += 4) {
        int2 e0 = epR[j];
        float w0 = __int_as_float(e0.y);
        ushort4 v0 = *(const ushort4*)(emb + (size_t)e0.x * HID + l * 4);
        a0 += w0 * b2f(v0.x); a1 += w0 * b2f(v0.y); a2 += w0 * b2f(v0.z); a3 += w0 * b2f(v0.w);
    }
    float4 st = { a0 + c0 + d0 + g0, a1 + c1 + d1 + g1,
                  a2 + c2 + d2 + g2, a3 + c3 + d3 + g3 };
    ((float4*)lacc[wv])[l] = st;
    __syncthreads();
    int c = threadIdx.x;
    agg[(size_t)n * HID + c] = f2b(lacc[0][c] + lacc[1][c] + lacc[2][c] + lacc[3][c]);
}

// ---------- MFMA node update + fused patient readout; atomics slot-split ----------
__global__ __launch_bounds__(256) void k_update2(
        const unsigned short* __restrict__ A,
        const float* __restrict__ emb_mrna, const float* __restrict__ emb_mirna,
        const unsigned short* __restrict__ wb,
        const float* __restrict__ bias_mrna, const float* __restrict__ bias_mirna,
        const int* __restrict__ rowptrP, const int2* __restrict__ epP,
        float* __restrict__ acc_slot) {
    __shared__ float ht[16][HID + 1];
    __shared__ float wtile[16][BB];
    int row0 = blockIdx.x * 16;   // global row (NG space); NMRNA % 16 == 0, never straddles
    const float* emb; const unsigned short* Wb; const float* bias; int base;
    if (row0 < NMRNA) { emb = emb_mrna;  Wb = wb;             bias = bias_mrna;  base = 0; }
    else              { emb = emb_mirna; Wb = wb + HID * HID; bias = bias_mirna; base = NMRNA; }
    int tid = threadIdx.x;
    if (tid < 16 * BB) wtile[tid >> 4][tid & 15] = 0.f;
    __syncthreads();
    // build 16x16 pat weight tile from sorted pat-edge segments (LDS atomics, ~256 edges)
    int pbeg = rowptrP[row0], pend = rowptrP[row0 + 16];
    for (int j = pbeg + tid; j < pend; j += 256) {
        int2 e = epP[j];
        atomicAdd(&wtile[(e.x >> 4) - row0][e.x & 15], __int_as_float(e.y));
    }
    int wv = tid >> 6;
    int lane = tid & 63;
    int m = lane & 15;   // A row offset / D col offset
    int q = lane >> 4;   // quad: k = q*8 + j
    bf16x8 afrag[8];
    const unsigned short* arow = A + (size_t)(row0 + m) * HID + q * 8;
#pragma unroll
    for (int kk = 0; kk < 8; kk++)
        afrag[kk] = *(const bf16x8*)(arow + kk * 32);
    f32x4 acc[4];
#pragma unroll
    for (int t = 0; t < 4; t++) acc[t] = (f32x4){0.f, 0.f, 0.f, 0.f};
    int col_base = wv * 64;
#pragma unroll
    for (int t = 0; t < 4; t++) {
        const unsigned short* brow = Wb + (size_t)(col_base + t * 16 + m) * HID + q * 8;
#pragma unroll
        for (int kk = 0; kk < 8; kk++) {
            bf16x8 bfrag = *(const bf16x8*)(brow + kk * 32);
            acc[t] = __builtin_amdgcn_mfma_f32_16x16x32_bf16(afrag[kk], bfrag, acc[t], 0, 0, 0);
        }
    }
#pragma unroll
    for (int t = 0; t < 4; t++) {
        int col = col_base + t * 16 + m;
        float bv = bias[col];
#pragma unroll
        for (int r = 0; r < 4; r++) {
            int lrow = q * 4 + r;                                // local row 0..15
            size_t idxe = (size_t)(row0 - base + lrow) * HID + col;
            ht[lrow][col] = emb[idxe] + gelu_exact(acc[t][r] + bv);
        }
    }
    __syncthreads();
    // fused skinny matmul: per col c, 16 patients x 16 rows; slot-split atomics
    float* out = acc_slot + (size_t)(blockIdx.x & (NSLOT - 1)) * BB * HID;
    int c = tid;
    float hv[16];
#pragma unroll
    for (int r = 0; r < 16; r++) hv[r] = ht[r][c];
#pragma unroll
    for (int b = 0; b < BB; b++) {
        float s = 0.f;
#pragma unroll
        for (int r = 0; r < 16; r++) s += wtile[r][b] * hv[r];   // LDS broadcast
        atomicAdd(&out[b * HID + c], s);                         // 8x less contention
    }
}

// ================= head chain, column-parallel =================
__global__ __launch_bounds__(256) void k_head_a(
        const float* __restrict__ acc_slot, const float* __restrict__ pooled,
        const float* __restrict__ masksum,
        const float* __restrict__ proj_w, const float* __restrict__ proj_b,
        const float* __restrict__ wsi_w, const float* __restrict__ wsi_b,
        float* __restrict__ pg, float* __restrict__ wt) {
    __shared__ float red[256];
    __shared__ float accs[BB * (HID + 1)];
    int c = blockIdx.x;
    int t = threadIdx.x;
    int b = t & 15, kk = t >> 4;

    // slot-reduce acc_slot -> LDS (coalesced; each thread 16 elems x 8 slots)
    for (int j = t; j < BB * HID; j += 256) {
        float v = 0.f;
#pragma unroll
        for (int s = 0; s < NSLOT; s++) v += acc_slot[(size_t)s * BB * HID + j];
        accs[(j >> 8) * (HID + 1) + (j & 255)] = v;
    }
    __syncthreads();

    const float* wr = proj_w + (size_t)c * HID + kk * 16;
    const float* ax = accs + b * (HID + 1) + kk * 16;
    float s = 0.f;
#pragma unroll
    for (int i = 0; i < 16; i += 4) {
        float4 w4 = *(const float4*)(wr + i);
        s += ax[i] * w4.x + ax[i + 1] * w4.y + ax[i + 2] * w4.z + ax[i + 3] * w4.w;
    }
    float tot = kred(s, red, b, kk);
    if (kk == 0) pg[(size_t)b * HID + c] = gelu_exact(tot + proj_b[c]);

    const float* wr2 = wsi_w + (size_t)c * PD + kk * 64;
    const float* xr2 = pooled + (size_t)b * PD + kk * 64;
    float s2 = 0.f;
#pragma unroll
    for (int i = 0; i < 64; i += 4) {
        float4 w4 = *(const float4*)(wr2 + i);
        float4 x4 = *(const float4*)(xr2 + i);
        s2 += x4.x * w4.x + x4.y * w4.y + x4.z * w4.z + x4.w * w4.w;
    }
    float tot2 = kred(s2, red, b, kk);
    if (kk == 0) {
        float sm = masksum[b];
        float denom = fmaxf(sm, 1.0f);
        wt[(size_t)b * HID + c] = gelu_exact(tot2 / denom + wsi_b[c] * (sm / denom));
    }
}

__global__ __launch_bounds__(256) void k_head_b(
        const float* __restrict__ wt,
        const float* __restrict__ mlp_w, const float* __restrict__ mlp_b,
        float* __restrict__ ml) {
    __shared__ float red[256];
    int c = blockIdx.x;
    int t = threadIdx.x;
    int b = t & 15, kk = t >> 4;
    const float* wr = mlp_w + (size_t)c * HID + kk * 16;
    const float* xr = wt + (size_t)b * HID + kk * 16;
    float s = 0.f;
#pragma unroll
    for (int i = 0; i < 16; i += 4) {
        float4 w4 = *(const float4*)(wr + i);
        float4 x4 = *(const float4*)(xr + i);
        s += x4.x * w4.x + x4.y * w4.y + x4.z * w4.z + x4.w * w4.w;
    }
    float tot = kred(s, red, b, kk);
    if (kk == 0) ml[(size_t)b * HID + c] = gelu_exact(tot + mlp_b[c]);
}

__global__ __launch_bounds__(256) void k_head_c(
        const float* __restrict__ pg, const float* __restrict__ ml,
        const float* __restrict__ ln_g, const float* __restrict__ ln_b,
        const float* __restrict__ wln_g, const float* __restrict__ wln_b,
        const float* __restrict__ omics_w, const float* __restrict__ omics_b,
        const float* __restrict__ fuse_b2,
        float* __restrict__ vecbuf, float* __restrict__ out_omics,
        float* __restrict__ out_fused) {
    __shared__ float red[256];
    int b = blockIdx.x, c = threadIdx.x;
    if (c < NBINS) out_fused[b * NBINS + c] = fuse_b2[c];
    float g = pg[(size_t)b * HID + c];
    float mean = block_reduce_sum(g, red) * (1.0f / HID);
    float d = g - mean;
    float var = block_reduce_sum(d * d, red) * (1.0f / HID);
    float patv = d * rsqrtf(var + 1e-5f) * ln_g[c] + ln_b[c];
    vecbuf[(size_t)b * (2 * HID) + c] = patv;
    for (int o = 0; o < NBINS; o++) {
        float r = block_reduce_sum(patv * omics_w[o * HID + c], red);
        if (c == 0) out_omics[b * NBINS + o] = r + omics_b[o];
    }
    float m = ml[(size_t)b * HID + c];
    mean = block_reduce_sum(m, red) * (1.0f / HID);
    d = m - mean;
    var = block_reduce_sum(d * d, red) * (1.0f / HID);
    vecbuf[(size_t)b * (2 * HID) + HID + c] = d * rsqrtf(var + 1e-5f) * wln_g[c] + wln_b[c];
}

__global__ __launch_bounds__(256) void k_head_d(
        const float* __restrict__ vecbuf,
        const float* __restrict__ fuse_w1, const float* __restrict__ fuse_b1,
        const float* __restrict__ fuse_w2,
        float* __restrict__ out_fused) {
    __shared__ float red[256];
    int c = blockIdx.x;
    int t = threadIdx.x;
    int b = t & 15, kk = t >> 4;
    const float* wr = fuse_w1 + (size_t)c * (2 * HID) + kk * 32;
    const float* xr = vecbuf + (size_t)b * (2 * HID) + kk * 32;
    float s = 0.f;
#pragma unroll
    for (int i = 0; i < 32; i += 4) {
        float4 w4 = *(const float4*)(wr + i);
        float4 x4 = *(const float4*)(xr + i);
        s += x4.x * w4.x + x4.y * w4.y + x4.z * w4.z + x4.w * w4.w;
    }
    float tot = kred(s, red, b, kk);
    if (kk == 0) {
        float h1 = gelu_exact(tot + fuse_b1[c]);
#pragma unroll
        for (int o = 0; o < NBINS; o++)
            atomicAdd(&out_fused[b * NBINS + o], h1 * fuse_w2[o * HID + c]);
    }
}

extern "C" void kernel_launch(void* const* d_in, const int* in_sizes, int n_in,
                              void* d_out, int out_size, void* d_ws, size_t ws_size,
                              hipStream_t stream) {
    const float* emb_mirna  = (const float*)d_in[0];
    const float* emb_mrna   = (const float*)d_in[1];
    const float* w_mir2mrna = (const float*)d_in[2];
    const float* w_mrna2mir = (const float*)d_in[3];
    const float* w_mrna2pat = (const float*)d_in[4];
    const float* w_mir2pat  = (const float*)d_in[5];
    const float* reg_w_mrna = (const float*)d_in[6];
    const float* reg_b_mrna = (const float*)d_in[7];
    const float* reg_w_mirna= (const float*)d_in[8];
    const float* reg_b_mirna= (const float*)d_in[9];
    const float* proj_w     = (const float*)d_in[10];
    const float* proj_b     = (const float*)d_in[11];
    const float* ln_g       = (const float*)d_in[12];
    const float* ln_b       = (const float*)d_in[13];
    const float* omics_w    = (const float*)d_in[14];
    const float* omics_b    = (const float*)d_in[15];
    const float* wsi_w      = (const float*)d_in[16];
    const float* wsi_b      = (const float*)d_in[17];
    const float* mlp_w      = (const float*)d_in[18];
    const float* mlp_b      = (const float*)d_in[19];
    const float* wln_g      = (const float*)d_in[20];
    const float* wln_b      = (const float*)d_in[21];
    const float* fuse_w1    = (const float*)d_in[22];
    const float* fuse_b1    = (const float*)d_in[23];
    const float* fuse_w2    = (const float*)d_in[24];
    const float* fuse_b2    = (const float*)d_in[25];
    const float* patches    = (const float*)d_in[26];
    const float* mask       = (const float*)d_in[27];
    const int* src_m2M = (const int*)d_in[28];
    const int* dst_m2M = (const int*)d_in[29];
    const int* src_M2m = (const int*)d_in[30];
    const int* dst_M2m = (const int*)d_in[31];
    const int* src_M2p = (const int*)d_in[32];
    const int* dst_M2p = (const int*)d_in[33];
    const int* src_m2p = (const int*)d_in[34];
    const int* dst_m2p = (const int*)d_in[35];

    float* ws = (float*)d_ws;
    size_t off = 0;
    // no host memset: acc_slot zeroed by k_front section; pooled/masksum fully overwritten
    float* acc_slot    = ws + off; off += (size_t)NSLOT * BB * HID;   // 32768
    float* pooled      = ws + off; off += (size_t)BB * PD;            // 16384
    float* masksum     = ws + off; off += BB;                         // 16
    float* pooled_part = ws + off; off += (size_t)32 * BB * PD;       // 524288
    float* maskp       = ws + off; off += 32 * BB;                    // 512
    unsigned short* agg_bf = (unsigned short*)(ws + off); off += (size_t)NG * HID / 2;
    unsigned short* wb     = (unsigned short*)(ws + off); off += (size_t)2 * HID * HID / 2;
    unsigned short* embB_mir  = (unsigned short*)(ws + off); off += (size_t)NMIR * HID / 2;
    unsigned short* embB_mrna = (unsigned short*)(ws + off); off += (size_t)NMRNA * HID / 2;
    float* pg       = ws + off; off += (size_t)BB * HID;
    float* wt       = ws + off; off += (size_t)BB * HID;
    float* ml       = ws + off; off += (size_t)BB * HID;
    float* vecbuf   = ws + off; off += (size_t)BB * 2 * HID;
    int* histR      = (int*)(ws + off); off += (size_t)NBR * NG;
    int* histP      = (int*)(ws + off); off += (size_t)NBP * NG;
    int* baseR      = (int*)(ws + off); off += (size_t)NBR * NG;   // relative
    int* baseP      = (int*)(ws + off); off += (size_t)NBP * NG;   // relative
    int* cntR       = (int*)(ws + off); off += NG;
    int* cntP       = (int*)(ws + off); off += NG;
    int* rowptrR    = (int*)(ws + off); off += NG + 2;
    int* rowptrP    = (int*)(ws + off); off += NG + 2;
    int2* epR       = (int2*)(ws + off); off += (size_t)2 * (2 * EREG);
    int2* epP       = (int2*)(ws + off); off += (size_t)2 * (EPM + EPI);

    float* out_fused = (float*)d_out;               // [16,4]
    float* out_omics = (float*)d_out + BB * NBINS;  // [16,4]

    // 1. fused front: pool(no atomics) + emb->bf16 + f2b + zero-acc + hist
    k_front<<<FR_TOTAL, 1024, 0, stream>>>(
        patches, mask, pooled_part, maskp,
        emb_mirna, emb_mrna, embB_mir, embB_mrna,
        reg_w_mrna, reg_w_mirna, wb, acc_slot,
        dst_m2M, dst_M2m, src_M2p, src_m2p, histR, histP);

    // 2-4. counting-sort CSR finish (+ pooled/masksum reduce inside colsum)
    k_colsum<<<2 * CS_B + PR_B, 256, 0, stream>>>(
        histR, histP, baseR, baseP, cntR, cntP,
        pooled_part, maskp, pooled, masksum);
    k_scan_small<<<2, 1024, 0, stream>>>(cntR, cntP, rowptrR, rowptrP);
    k_place<<<NBR + NBP, 1024, 0, stream>>>(
        src_m2M, dst_m2M, w_mir2mrna, src_M2m, dst_M2m, w_mrna2mir,
        src_M2p, dst_M2p, w_mrna2pat, src_m2p, dst_m2p, w_mir2pat,
        baseR, baseP, rowptrR, rowptrP, epR, epP);

    // 5. CSR gather from bf16 embeddings
    k_gather2<<<NG, 256, 0, stream>>>(embB_mir, embB_mrna, rowptrR, epR, agg_bf);

    // 6. MFMA node update + fused patient readout (slot-split atomics)
    k_update2<<<NG / 16, 256, 0, stream>>>(agg_bf, emb_mrna, emb_mirna, wb,
                                           reg_b_mrna, reg_b_mirna,
                                           rowptrP, epP, acc_slot);

    // 7-10. head chain, column-parallel (head_a slot-reduces acc)
    k_head_a<<<HID, 256, 0, stream>>>(acc_slot, pooled, masksum,
                                      proj_w, proj_b, wsi_w, wsi_b, pg, wt);
    k_head_b<<<HID, 256, 0, stream>>>(wt, mlp_w, mlp_b, ml);
    k_head_c<<<BB, 256, 0, stream>>>(pg, ml, ln_g, ln_b, wln_g, wln_b,
                                     omics_w, omics_b, fuse_b2,
                                     vecbuf, out_omics, out_fused);
    k_head_d<<<HID, 256, 0, stream>>>(vecbuf, fuse_w1, fuse_b1, fuse_w2, out_fused);
}